// Round 5
// baseline (358.780 us; speedup 1.0000x reference)
//
#include <hip/hip_runtime.h>
#include <cstdint>
#include <cstddef>

#define HIDDEN 1024
#define NH 16
#define NKV 8
#define HD 128
#define SEQ 2048
#define BATCH 2
#define NTOK (BATCH*SEQ)        /* 4096 */

typedef __bf16 bf16x8 __attribute__((ext_vector_type(8)));
typedef float f32x4 __attribute__((ext_vector_type(4)));

__device__ __forceinline__ unsigned short f2bf(float f) {
  unsigned int u = __float_as_uint(f);
  u += 0x7FFFu + ((u >> 16) & 1u);          // round-to-nearest-even
  return (unsigned short)(u >> 16);
}
__device__ __forceinline__ float bf2f(unsigned short h) {
  return __uint_as_float(((unsigned int)h) << 16);
}

#if __has_builtin(__builtin_amdgcn_exp2f)
#define EXP2(x) __builtin_amdgcn_exp2f(x)
#else
#define EXP2(x) exp2f(x)
#endif

// async global->LDS, 16B per lane; LDS dest = uniform base + lane*16
__device__ __forceinline__ void glds16(const unsigned short* g, unsigned short* l) {
  __builtin_amdgcn_global_load_lds(
      (const __attribute__((address_space(1))) unsigned int*)g,
      (__attribute__((address_space(3))) unsigned int*)l, 16, 0, 0);
}

// s_waitcnt immediates (gfx9/CDNA: vmcnt[3:0]+[15:14], exp[6:4], lgkm[11:8])
#define WAIT_VM8()   __builtin_amdgcn_s_waitcnt(0x0F78)  /* vmcnt<=8 */
#define WAIT_VM6()   __builtin_amdgcn_s_waitcnt(0x0F76)  /* vmcnt<=6 */
#define WAIT_VM4()   __builtin_amdgcn_s_waitcnt(0x0F74)  /* vmcnt<=4 */
#define WAIT_VM0()   __builtin_amdgcn_s_waitcnt(0x0F70)  /* vmcnt<=0 */
#define WAIT_LGKM0() __builtin_amdgcn_s_waitcnt(0xC07F)  /* lgkmcnt<=0 */
#define BARRIER()    __builtin_amdgcn_s_barrier()

// adjacent-lane (xor 1) exchange-add via quad_perm [1,0,3,2]
__device__ __forceinline__ float dpp_addx1(float x) {
  int v = __builtin_amdgcn_update_dpp(0, __float_as_int(x), 0xB1, 0xF, 0xF, true);
  return x + __int_as_float(v);
}

// ---- all-weights transpose-convert + hs convert, ONE launch ----
__global__ __launch_bounds__(256) void tcvt_all_kernel(
    const float* __restrict__ Wq, const float* __restrict__ Wk,
    const float* __restrict__ Wv, const float* __restrict__ Wo,
    const float* __restrict__ hs,
    unsigned short* __restrict__ wqkvt, unsigned short* __restrict__ wot,
    unsigned short* __restrict__ hsb) {
  const int i = blockIdx.x;
  const int tx = threadIdx.x, ty = threadIdx.y;
  if (i >= 6144) {                           // hs convert: 1024 blocks x 4096 elems
    const int t = ty*32 + tx;
    const size_t base = (size_t)(i - 6144) * 1024;   // in float4 units
#pragma unroll
    for (int j = 0; j < 4; ++j) {
      const size_t idx = base + j*256 + t;
      float4 v = ((const float4*)hs)[idx];
      ushort4 o;
      o.x = f2bf(v.x); o.y = f2bf(v.y); o.z = f2bf(v.z); o.w = f2bf(v.w);
      ((ushort4*)hsb)[idx] = o;
    }
    return;
  }
  __shared__ float tl[32][33];
  const float* src; unsigned short* dst; int R, C, r0, c0;
  if (i < 2048)      { int l = i;        src = Wq; dst = wqkvt;                      R = 1024; C = 2048; r0 = (l & 31)*32; c0 = (l >> 5)*32; }
  else if (i < 3072) { int l = i - 2048; src = Wk; dst = wqkvt + (size_t)2048*1024;  R = 1024; C = 1024; r0 = (l & 31)*32; c0 = (l >> 5)*32; }
  else if (i < 4096) { int l = i - 3072; src = Wv; dst = wqkvt + (size_t)3072*1024;  R = 1024; C = 1024; r0 = (l & 31)*32; c0 = (l >> 5)*32; }
  else               { int l = i - 4096; src = Wo; dst = wot;                        R = 2048; C = 1024; r0 = (l & 63)*32; c0 = (l >> 6)*32; }
#pragma unroll
  for (int k = 0; k < 4; ++k)
    tl[ty + 8*k][tx] = src[(size_t)(r0 + ty + 8*k)*C + c0 + tx];
  __syncthreads();
#pragma unroll
  for (int k = 0; k < 4; ++k)
    dst[(size_t)(c0 + ty + 8*k)*R + r0 + tx] = f2bf(tl[tx][ty + 8*k]);
}

// -------- QKV GEMM (128x128, BK=64, async dbuf) + fused norm/rope/vtrans --------
// R12: vt8 written in kappa-permuted kv order (within each 64-kv block:
// kv = s2*32 + e2*16 + s1*8 + s0*4 + e1*2 + e0 for slot (slice s, elem e))
// so the attn PV B-fragment (P^T) needs NO cross-lane repack.
__global__ __launch_bounds__(256) void gemm_qkv_fused_kernel(
    const unsigned short* __restrict__ A,      // hs bf16 [4096][1024]
    const unsigned short* __restrict__ Bt,     // wqkvt bf16 [4096][1024]
    const float* __restrict__ qw, const float* __restrict__ kw,
    const int* __restrict__ pos_ids,
    unsigned short* __restrict__ q_l,
    unsigned short* __restrict__ k_l,
    unsigned short* __restrict__ vt8) {
  constexpr int BM = 128, BK = 64, K = 1024, NIT = K/BK;
  __shared__ __align__(16) char smem[70144];   // 68.5 KB -> 2 blocks/CU
  unsigned short* As0 = (unsigned short*)smem;           // 2 x 16 KB
  unsigned short* Bs0 = (unsigned short*)(smem + 32768); // 2 x 16 KB
  float* ftile = (float*)smem;                           // 128 x 136 fp32 (68 KB)
  float* rinv  = (float*)(smem + 69632);                 // 128 fp32

  const int t = threadIdx.x, lane = t & 63, w = t >> 6;
  const int l15 = lane & 15, l4 = lane >> 4;
  const int wr = (w >> 1)*64, wc = (w & 1)*64;
  const int m0 = blockIdx.x * BM, n0 = blockIdx.y * 128;
  const unsigned short* Ab = A + (size_t)m0*K;
  const unsigned short* Bb = Bt + (size_t)n0*K;

  const f32x4 vzero = {0.f, 0.f, 0.f, 0.f};
  f32x4 acc[4][4];
#pragma unroll
  for (int i = 0; i < 4; ++i)
#pragma unroll
    for (int j = 0; j < 4; ++j) acc[i][j] = vzero;

#pragma unroll
  for (int i = 0; i < 4; ++i) {
    const int c = (w*4 + i)*64 + lane;
    glds16(Ab + (size_t)(c >> 3)*K + (c & 7)*8, As0 + (size_t)(w*4 + i)*512);
  }
#pragma unroll
  for (int i = 0; i < 4; ++i) {
    const int c = (w*4 + i)*64 + lane;
    glds16(Bb + (size_t)(c >> 3)*K + (c & 7)*8, Bs0 + (size_t)(w*4 + i)*512);
  }

  for (int kb = 0; kb < NIT; ++kb) {
    const int cur = kb & 1;
    WAIT_LGKM0(); BARRIER();
    if (kb + 1 < NIT) {
      const int kn = (kb + 1) * BK;
      const int nb = (cur^1)*8192;
#pragma unroll
      for (int i = 0; i < 4; ++i) {
        const int c = (w*4 + i)*64 + lane;
        glds16(Ab + (size_t)(c >> 3)*K + kn + (c & 7)*8, As0 + nb + (size_t)(w*4 + i)*512);
      }
#pragma unroll
      for (int i = 0; i < 4; ++i) {
        const int c = (w*4 + i)*64 + lane;
        glds16(Bb + (size_t)(c >> 3)*K + kn + (c & 7)*8, Bs0 + nb + (size_t)(w*4 + i)*512);
      }
      WAIT_VM8();
    } else {
      WAIT_VM0();
    }
    BARRIER();

    const unsigned short* Ac = As0 + cur*8192;
    const unsigned short* Bc = Bs0 + cur*8192;
#pragma unroll
    for (int kk = 0; kk < 2; ++kk) {
      const int kc = kk*4 + l4;
      bf16x8 af[4], bfr[4];
#pragma unroll
      for (int i = 0; i < 4; ++i) {
        int m = wr + i*16 + l15;
        af[i] = *(const bf16x8*)(Ac + ((size_t)m*8 + kc)*8);
      }
#pragma unroll
      for (int j = 0; j < 4; ++j) {
        int n = wc + j*16 + l15;
        bfr[j] = *(const bf16x8*)(Bc + ((size_t)n*8 + kc)*8);
      }
#pragma unroll
      for (int i = 0; i < 4; ++i)
#pragma unroll
        for (int j = 0; j < 4; ++j)
          acc[i][j] = __builtin_amdgcn_mfma_f32_16x16x32_bf16(af[i], bfr[j], acc[i][j], 0, 0, 0);
    }
  }

  // ---- epilogue: spill C-tile to LDS fp32 [128][136] ----
  WAIT_LGKM0(); BARRIER();
#pragma unroll
  for (int i = 0; i < 4; ++i)
#pragma unroll
    for (int j = 0; j < 4; ++j)
#pragma unroll
      for (int r = 0; r < 4; ++r) {
        const int row = wr + i*16 + l4*4 + r;
        const int col = wc + j*16 + l15;
        ftile[row*136 + col] = acc[i][j][r];
      }
  WAIT_LGKM0(); BARRIER();

  const int ny = n0 >> 7;                    // 0..15 q-head, 16..23 k-head, 24..31 v-head
  const int S0 = m0 & (SEQ-1);
  const int bb = m0 >> 11;

  if (ny < 24) {
    const bool isQ = ny < 16;
    {
      const int row = t >> 1, h2 = t & 1;
      const float* fr = ftile + row*136 + h2*64;
      float ssq = 0.f;
#pragma unroll
      for (int c = 0; c < 16; ++c) {
        float4 v = *(const float4*)(fr + 4*c);
        ssq += v.x*v.x + v.y*v.y + v.z*v.z + v.w*v.w;
      }
      ssq = dpp_addx1(ssq);
      if (h2 == 0) rinv[row] = rsqrtf(ssq*(1.0f/128.0f) + 1e-6f);
    }
    WAIT_LGKM0(); BARRIER();
    const float* wgt = isQ ? qw : kw;
    const int d = t & 127, rh = t >> 7;
    const float wd = wgt[d];
    const float w2 = wgt[d ^ 64];
    const float sgn = (d < 64) ? -1.f : 1.f;
    const float sOut = isQ ? 0.12751744f : 1.f;     // (1/sqrt(128))*log2(e) folded into q
    const float invf = exp2f(-(float)(d & 63) * 0.31143075889569023f);
    const int pos0 = pos_ids[S0 + rh*64];
    float cs, sn, dc, dsn;
    __sincosf((float)pos0 * invf, &sn, &cs);
    __sincosf(invf, &dsn, &dc);
    const int head = isQ ? ny : (ny - 16);
    unsigned short* dstb = isQ ? (q_l + ((size_t)(bb*NH + head)*SEQ + S0)*HD)
                               : (k_l + ((size_t)(bb*NKV + head)*SEQ + S0)*HD);
#pragma unroll 4
    for (int k = 0; k < 64; ++k) {
      const int row = rh*64 + k;
      const float r  = rinv[row];
      const float x1 = ftile[row*136 + d];
      const float x2 = ftile[row*136 + (d ^ 64)];
      const float y1 = x1*r*wd, y2 = x2*r*w2;
      const float o  = (y1*cs + sgn*(y2*sn)) * sOut;
      dstb[(size_t)row*HD + d] = f2bf(o);
      const float c2 = cs*dc - sn*dsn;       // rotate: pos -> pos+1
      sn = sn*dc + cs*dsn; cs = c2;
    }
  } else {
    // V-epilogue: kappa-permuted store. Slot (slice sl, elem s8) holds
    // C-row = blk*64 + s2*32 + e2*16 + s1*8 + s0*4 + e1*2 + e0.
    const int vh = ny - 24;
    unsigned short* vb = vt8 + (size_t)(bb*NKV + vh)*HD*SEQ;
    const int d = t & 127, sbh = t >> 7;
#pragma unroll
    for (int sb = 0; sb < 8; ++sb) {
      const int sl = sbh*8 + sb;
      const int blk = sl >> 3, s = sl & 7;
      const int base_r = blk*64 + ((s>>2)<<5) + (((s>>1)&1)<<3) + ((s&1)<<2);
      union { unsigned short u[8]; uint4 q; } pk;
#pragma unroll
      for (int s8 = 0; s8 < 8; ++s8) {
        const int row = base_r + ((s8>>2)<<4) + (((s8>>1)&1)<<1) + (s8&1);
        pk.u[s8] = f2bf(ftile[row*136 + d]);
      }
      *(uint4*)(vb + ((size_t)((S0 >> 3) + sl)*128 + d)*8) = pk.q;
    }
  }
}

// ------------- bf16 GEMM (out-proj): 128x128 tile, fp32 out -------------
__global__ __launch_bounds__(256) void gemm_out_kernel(
    const unsigned short* __restrict__ A,
    const unsigned short* __restrict__ Bt,
    float* __restrict__ Cout, int M, int N, int K) {
  constexpr int BK = 64;
  __shared__ unsigned short As[2][128*BK];   // 2 x 16 KB
  __shared__ unsigned short Bs[2][128*BK];   // 2 x 16 KB  -> 64 KB, 2 blocks/CU
  const int t = threadIdx.x, lane = t & 63, w = t >> 6;
  const int l15 = lane & 15, l4 = lane >> 4;
  const int wr = (w >> 1)*64, wc = (w & 1)*64;
  const int m0 = blockIdx.y * 128, n0 = blockIdx.x * 128;
  const unsigned short* Ab = A + (size_t)m0*K;
  const unsigned short* Bb = Bt + (size_t)n0*K;

  const f32x4 vzero = {0.f, 0.f, 0.f, 0.f};
  f32x4 acc[4][4];
#pragma unroll
  for (int i = 0; i < 4; ++i)
#pragma unroll
    for (int j = 0; j < 4; ++j) acc[i][j] = vzero;

  const int NIT = K / BK;
#pragma unroll
  for (int i = 0; i < 4; ++i) {
    const int c = (w*4 + i)*64 + lane;
    glds16(Ab + (size_t)(c >> 3)*K + (c & 7)*8, &As[0][(size_t)(w*4 + i)*512]);
  }
#pragma unroll
  for (int i = 0; i < 4; ++i) {
    const int c = (w*4 + i)*64 + lane;
    glds16(Bb + (size_t)(c >> 3)*K + (c & 7)*8, &Bs[0][(size_t)(w*4 + i)*512]);
  }

  for (int kb = 0; kb < NIT; ++kb) {
    const int cur = kb & 1;
    WAIT_LGKM0(); BARRIER();
    if (kb + 1 < NIT) {
      const int kn = (kb + 1) * BK;
#pragma unroll
      for (int i = 0; i < 4; ++i) {
        const int c = (w*4 + i)*64 + lane;
        glds16(Ab + (size_t)(c >> 3)*K + kn + (c & 7)*8, &As[cur^1][(size_t)(w*4 + i)*512]);
      }
#pragma unroll
      for (int i = 0; i < 4; ++i) {
        const int c = (w*4 + i)*64 + lane;
        glds16(Bb + (size_t)(c >> 3)*K + kn + (c & 7)*8, &Bs[cur^1][(size_t)(w*4 + i)*512]);
      }
      WAIT_VM8();
    } else {
      WAIT_VM0();
    }
    BARRIER();

#pragma unroll
    for (int kk = 0; kk < 2; ++kk) {
      const int kc = kk*4 + l4;
      bf16x8 af[4], bfr[4];
#pragma unroll
      for (int i = 0; i < 4; ++i) {
        int m = wr + i*16 + l15;
        af[i] = *(const bf16x8*)(&As[cur][((size_t)m*8 + kc)*8]);
      }
#pragma unroll
      for (int j = 0; j < 4; ++j) {
        int n = wc + j*16 + l15;
        bfr[j] = *(const bf16x8*)(&Bs[cur][((size_t)n*8 + kc)*8]);
      }
#pragma unroll
      for (int i = 0; i < 4; ++i)
#pragma unroll
        for (int j = 0; j < 4; ++j)
          acc[i][j] = __builtin_amdgcn_mfma_f32_16x16x32_bf16(af[i], bfr[j], acc[i][j], 0, 0, 0);
    }
  }
#pragma unroll
  for (int i = 0; i < 4; ++i)
#pragma unroll
    for (int j = 0; j < 4; ++j)
#pragma unroll
      for (int r = 0; r < 4; ++r) {
        int row = m0 + wr + i*16 + l4*4 + r;
        int col = n0 + wc + j*16 + l15;
        Cout[(size_t)row*N + col] = acc[i][j][r];
      }
}

// ------------- Flash attention, causal, GQA, KV-SPLIT -------------
// R12: swapped QK^T (S^T = mfma(K,Q)) + kappa-permuted vt8 -> the PV
// B-fragment (P^T) is the lane's OWN sacc values packed to bf16: zero
// LDS traffic for P (was 32 ds_write_b16 + 4 ds_read_b128 per iter).
// V single-buffered (staged at iter start, counted-vmcnt wait under
// QK^T+softmax). LDS 48 KB -> 3 blocks/CU (was 2 at 72 KB).
__global__ __launch_bounds__(256, 3) void attn_kernel(
    const unsigned short* __restrict__ q_l,
    const unsigned short* __restrict__ k_l,
    const unsigned short* __restrict__ vt8,
    unsigned short* __restrict__ o_part,   // [2][B][NH][SEQ][HD] bf16
    float* __restrict__ l_part) {          // [2][B][NH][SEQ] fp32
  __shared__ __align__(16) char smem[49152];
  unsigned short* Ks0 = (unsigned short*)smem;            // 2 x 16 KB dbuf
  unsigned short* Vts = (unsigned short*)(smem + 32768);  // 16 KB single

  const int t = threadIdx.x;
  const int lane = t & 63;
  const int w = t >> 6;
  const int l15 = lane & 15, l4 = lane >> 4;
  const int hb = blockIdx.x;                 // h + 16*b (fast dim: K/V L2 share)
  const int h = hb & 15, b = hb >> 4;
  const int y = blockIdx.y;                  // 0..31
  const int qt = 15 - (y >> 1);              // longest first
  const int half = y & 1;
  const int kvh = h >> 1;
  const int q0 = qt * 128;
  const int kt0 = half ? (qt + 1) : 0;
  const int kt1 = half ? (2*qt + 2) : (qt + 1);

  const unsigned short* Kg = k_l + ((size_t)(b*NKV + kvh)*SEQ)*HD;
  const unsigned short* Vg = vt8 + (size_t)(b*NKV + kvh)*HD*SEQ;
  const unsigned short* Qbase = q_l + ((size_t)(b*NH + h)*SEQ)*HD;

  const f32x4 vzero = {0.f,0.f,0.f,0.f};

  // Q fragments in registers (already scaled by 1/sqrt(d)*log2e)
  bf16x8 qf[2][4];
#pragma unroll
  for (int i = 0; i < 2; ++i) {
    const int row = q0 + w*32 + i*16 + l15;
    const unsigned short* Qp = Qbase + (size_t)row*HD;
#pragma unroll
    for (int kk = 0; kk < 4; ++kk)
      qf[i][kk] = *(const bf16x8*)(Qp + kk*32 + l4*8);
  }

  f32x4 oacc[2][8];                          // O^T: [q-subtile][d-tile]
#pragma unroll
  for (int i = 0; i < 2; ++i)
#pragma unroll
    for (int jd = 0; jd < 8; ++jd) oacc[i][jd] = vzero;
  float lrun[2] = {0.f, 0.f};                // per-lane partial row sums

  // prologue: issue K(kt0) into buf 0
  {
    const int k00 = kt0 * 64;
#pragma unroll
    for (int i = 0; i < 4; ++i) {
      const int kc = w*4 + i;
      const int m = lane ^ (kc & 7);
      glds16(Kg + (size_t)(k00 + m)*HD + kc*8, Ks0 + (size_t)kc*64*8);
    }
  }

#pragma unroll 1
  for (int kt = kt0; kt < kt1; ++kt) {
    const int cur = (kt - kt0) & 1;
    const int k0 = kt * 64;
    // own K(kt) loads landed; barrier => all waves' K(kt) staged AND
    // all waves finished PV(kt-1) reads of the single V buffer.
    WAIT_VM0(); BARRIER();

    // issue V(kt) (4/wave, first) then K(kt+1) (4/wave) -> counted waits
#pragma unroll
    for (int i = 0; i < 4; ++i) {
      const int id = w*4 + i;
      const int skc = id >> 1, hh = id & 1;
      const int d = (hh*64 + lane) ^ skc;
      glds16(Vg + ((size_t)((k0 >> 3) + skc)*128 + d)*8, Vts + (size_t)(skc*128 + hh*64)*8);
    }
    const bool pk_ = (kt + 1 < kt1);
    if (pk_) {
      const int kn = k0 + 64;
      unsigned short* Ksn = Ks0 + (cur^1)*8192;
#pragma unroll
      for (int i = 0; i < 4; ++i) {
        const int kc = w*4 + i;
        const int m = lane ^ (kc & 7);
        glds16(Kg + (size_t)(kn + m)*HD + kc*8, Ksn + (size_t)kc*64*8);
      }
    }

    const unsigned short* KsC = Ks0 + cur*8192;

    // S^T = K Q^T (lane: q = l15 within subtile, kv = j*16 + l4*4 + r)
    f32x4 sacc[4][2];
#pragma unroll
    for (int j = 0; j < 4; ++j)
#pragma unroll
      for (int i = 0; i < 2; ++i) sacc[j][i] = vzero;
    __builtin_amdgcn_s_setprio(1);
#pragma unroll
    for (int kk = 0; kk < 4; ++kk) {
      const int kc = kk*4 + l4;
      bf16x8 kb[4];
#pragma unroll
      for (int j = 0; j < 4; ++j) {
        int n = j*16 + l15;
        kb[j] = *(const bf16x8*)(KsC + ((size_t)kc*64 + (n ^ (kc & 7)))*8);
      }
#pragma unroll
      for (int j = 0; j < 4; ++j)
#pragma unroll
        for (int i = 0; i < 2; ++i)
          sacc[j][i] = __builtin_amdgcn_mfma_f32_16x16x32_bf16(kb[j], qf[i][kk], sacc[j][i], 0,0,0);
    }
    __builtin_amdgcn_s_setprio(0);

    // P = exp2(S) (no max); causal mask on the diag tiles
    const bool diag = (kt >= 2*qt);
#pragma unroll
    for (int j = 0; j < 4; ++j)
#pragma unroll
      for (int i = 0; i < 2; ++i)
#pragma unroll
        for (int r = 0; r < 4; ++r) {
          float sv = sacc[j][i][r];
          if (diag) {
            const int kvg = k0 + j*16 + l4*4 + r;
            const int qg  = q0 + w*32 + i*16 + l15;
            sv = (kvg > qg) ? -INFINITY : sv;
          }
          float pv = EXP2(sv);
          sacc[j][i][r] = pv;
          lrun[i] += pv;
        }

    // V(kt) staged by all waves (keep K(kt+1) in flight)
    if (pk_) { WAIT_VM4(); } else { WAIT_VM0(); }
    BARRIER();

    // O^T += V^T P^T  (A = V^T frag from LDS, B = own packed P)
#pragma unroll
    for (int kk = 0; kk < 2; ++kk) {
      union { unsigned int u[4]; bf16x8 v; } pb[2];
#pragma unroll
      for (int i = 0; i < 2; ++i) {
        const f32x4 t0 = sacc[kk*2][i], t1 = sacc[kk*2+1][i];
        pb[i].u[0] = (__float_as_uint(t0[0]) >> 16) | (__float_as_uint(t0[1]) & 0xFFFF0000u);
        pb[i].u[1] = (__float_as_uint(t0[2]) >> 16) | (__float_as_uint(t0[3]) & 0xFFFF0000u);
        pb[i].u[2] = (__float_as_uint(t1[0]) >> 16) | (__float_as_uint(t1[1]) & 0xFFFF0000u);
        pb[i].u[3] = (__float_as_uint(t1[2]) >> 16) | (__float_as_uint(t1[3]) & 0xFFFF0000u);
      }
      const int s = kk*4 + l4;
      __builtin_amdgcn_s_setprio(1);
#pragma unroll
      for (int td = 0; td < 8; ++td) {
        const int dd = td*16 + l15;
        bf16x8 va = *(const bf16x8*)(Vts + ((size_t)s*128 + (dd ^ s))*8);
#pragma unroll
        for (int i = 0; i < 2; ++i)
          oacc[i][td] = __builtin_amdgcn_mfma_f32_16x16x32_bf16(va, pb[i].v, oacc[i][td], 0,0,0);
      }
      __builtin_amdgcn_s_setprio(0);
    }
  }

  // epilogue: reduce lrun across the 4 l4-groups, normalize, store O^T.
  unsigned short* ob = o_part + ((size_t)half*BATCH*NH*SEQ + (size_t)(b*NH + h)*SEQ)*HD;
  float* lb = l_part + (size_t)half*BATCH*NH*SEQ + (size_t)(b*NH + h)*SEQ;
#pragma unroll
  for (int i = 0; i < 2; ++i) {
    float lsum = lrun[i];
    lsum += __shfl_xor(lsum, 16, 64);
    lsum += __shfl_xor(lsum, 32, 64);
    const float inv = (lsum > 0.f) ? 1.0f / lsum : 0.f;
    const int row = q0 + w*32 + i*16 + l15;
    if (l4 == 0) lb[row] = lsum;
#pragma unroll
    for (int td = 0; td < 8; ++td) {
      union { unsigned int u[2]; uint2 q; } pk;
      const float v0 = oacc[i][td][0]*inv, v1 = oacc[i][td][1]*inv;
      const float v2 = oacc[i][td][2]*inv, v3 = oacc[i][td][3]*inv;
      pk.u[0] = (unsigned int)f2bf(v0) | ((unsigned int)f2bf(v1) << 16);
      pk.u[1] = (unsigned int)f2bf(v2) | ((unsigned int)f2bf(v3) << 16);
      *(uint2*)(ob + (size_t)row*HD + td*16 + l4*4) = pk.q;
    }
  }
}

// ------------- combine: attn_o = (la*Oa + lb*Ob) / (la+lb) -------------
__global__ __launch_bounds__(256) void combine_kernel(
    const unsigned short* __restrict__ o_part,  // [2][B*NH*SEQ][HD] bf16
    const float* __restrict__ l_part,           // [2][B*NH*SEQ] fp32
    unsigned short* __restrict__ attn_o) {      // [B][SEQ][NH*HD] bf16
  const int tid = blockIdx.x * 256 + threadIdx.x;  // 1,048,576 threads
  const int d8 = tid & 15;                    // 16 chunks of 8 d
  const int row = tid >> 4;                   // (b*NH+h)*SEQ + s
  const int s = row & (SEQ-1);
  const int bh = row >> 11;
  const int h = bh & 15, b = bh >> 4;
  const float la = l_part[row];
  const float lbv = l_part[BATCH*NH*SEQ + row];
  const float inv = 1.f / (la + lbv);
  const float wa = la * inv, wb = lbv * inv;
  const unsigned short* pa = o_part + (size_t)row*HD + d8*8;
  const unsigned short* pb = pa + (size_t)BATCH*NH*SEQ*HD;
  uint4 ua = *(const uint4*)pa;
  uint4 ub = *(const uint4*)pb;
  const unsigned short* ea = (const unsigned short*)&ua;
  const unsigned short* eb = (const unsigned short*)&ub;
  union { unsigned short u[8]; uint4 q; } o;
#pragma unroll
  for (int k = 0; k < 8; ++k)
    o.u[k] = f2bf(bf2f(ea[k])*wa + bf2f(eb[k])*wb);
  *(uint4*)(attn_o + ((size_t)(b*SEQ + s)*(NH*HD)) + h*HD + d8*8) = o.q;
}

extern "C" void kernel_launch(void* const* d_in, const int* in_sizes, int n_in,
                              void* d_out, int out_size, void* d_ws, size_t ws_size,
                              hipStream_t stream) {
  const float* hs = (const float*)d_in[0];
  const int* pos  = (const int*)d_in[1];
  const float* Wq = (const float*)d_in[2];
  const float* Wk = (const float*)d_in[3];
  const float* Wv = (const float*)d_in[4];
  const float* Wo = (const float*)d_in[5];
  const float* qw = (const float*)d_in[6];
  const float* kw = (const float*)d_in[7];
  float* out = (float*)d_out;
  char* ws = (char*)d_ws;

  unsigned short* attn_o = (unsigned short*)(ws + 0);                    // 16 MB
  unsigned short* wot    = (unsigned short*)(ws + ((size_t)16 << 20));   // 4 MB
  unsigned short* q_l    = (unsigned short*)(ws + ((size_t)20 << 20));   // 16 MB
  unsigned short* k_l    = (unsigned short*)(ws + ((size_t)36 << 20));   // 8 MB
  unsigned short* vt8    = (unsigned short*)(ws + ((size_t)44 << 20));   // 8 MB
  unsigned short* o_part = (unsigned short*)(ws + ((size_t)52 << 20));   // 32 MB
  unsigned short* hsb    = (unsigned short*)(ws + ((size_t)52 << 20));   // 8 MB (alias)
  unsigned short* wqkvt  = (unsigned short*)(ws + ((size_t)60 << 20));   // 8 MB (alias)
  float*          l_part = (float*)(ws + ((size_t)84 << 20));            // 512 KB

  // 1. all converts in one launch (weights transpose-convert + hs convert)
  tcvt_all_kernel<<<dim3(7168), dim3(32, 8), 0, stream>>>(Wq, Wk, Wv, Wo, hs, wqkvt, wot, hsb);
  // 2. QKV projection + fused RMSNorm/RoPE/V-transpose epilogue (kappa-permuted vt8)
  gemm_qkv_fused_kernel<<<dim3(32, 32), dim3(256), 0, stream>>>(hsb, wqkvt, qw, kw, pos, q_l, k_l, vt8);
  // 3. flash attention, swapped-QK^T + in-register P, 3 blocks/CU
  attn_kernel<<<dim3(32, 32), dim3(256), 0, stream>>>(q_l, k_l, vt8, o_part, l_part);
  // 3b. combine partials -> attn_o
  combine_kernel<<<dim3(4096), dim3(256), 0, stream>>>(o_part, l_part, attn_o);
  // 4. output projection: 128x128 tiles, grid (N/128=8, M/128=32) = 256 blocks
  gemm_out_kernel<<<dim3(8, 32), dim3(256), 0, stream>>>(attn_o, wot, out, 4096, 1024, 2048);
}

// Round 7
// 352.964 us; speedup vs baseline: 1.0165x; 1.0165x over previous
//
#include <hip/hip_runtime.h>
#include <cstdint>
#include <cstddef>

#define HIDDEN 1024
#define NH 16
#define NKV 8
#define HD 128
#define SEQ 2048
#define BATCH 2
#define NTOK (BATCH*SEQ)        /* 4096 */

typedef __bf16 bf16x8 __attribute__((ext_vector_type(8)));
typedef float f32x4 __attribute__((ext_vector_type(4)));

__device__ __forceinline__ unsigned short f2bf(float f) {
  unsigned int u = __float_as_uint(f);
  u += 0x7FFFu + ((u >> 16) & 1u);          // round-to-nearest-even
  return (unsigned short)(u >> 16);
}
__device__ __forceinline__ float bf2f(unsigned short h) {
  return __uint_as_float(((unsigned int)h) << 16);
}

#if __has_builtin(__builtin_amdgcn_exp2f)
#define EXP2(x) __builtin_amdgcn_exp2f(x)
#else
#define EXP2(x) exp2f(x)
#endif

// async global->LDS, 16B per lane; LDS dest = uniform base + lane*16
__device__ __forceinline__ void glds16(const unsigned short* g, unsigned short* l) {
  __builtin_amdgcn_global_load_lds(
      (const __attribute__((address_space(1))) unsigned int*)g,
      (__attribute__((address_space(3))) unsigned int*)l, 16, 0, 0);
}

// s_waitcnt immediates (gfx9/CDNA: vmcnt[3:0]+[15:14], exp[6:4], lgkm[11:8])
#define WAIT_VM8()   __builtin_amdgcn_s_waitcnt(0x0F78)  /* vmcnt<=8 */
#define WAIT_VM6()   __builtin_amdgcn_s_waitcnt(0x0F76)  /* vmcnt<=6 */
#define WAIT_VM4()   __builtin_amdgcn_s_waitcnt(0x0F74)  /* vmcnt<=4 */
#define WAIT_VM0()   __builtin_amdgcn_s_waitcnt(0x0F70)  /* vmcnt<=0 */
#define WAIT_LGKM0() __builtin_amdgcn_s_waitcnt(0xC07F)  /* lgkmcnt<=0 */
#define BARRIER()    __builtin_amdgcn_s_barrier()

// adjacent-lane (xor 1) exchange-add via quad_perm [1,0,3,2]
__device__ __forceinline__ float dpp_addx1(float x) {
  int v = __builtin_amdgcn_update_dpp(0, __float_as_int(x), 0xB1, 0xF, 0xF, true);
  return x + __int_as_float(v);
}

// ---- all-weights transpose-convert + hs convert, ONE launch ----
__global__ __launch_bounds__(256) void tcvt_all_kernel(
    const float* __restrict__ Wq, const float* __restrict__ Wk,
    const float* __restrict__ Wv, const float* __restrict__ Wo,
    const float* __restrict__ hs,
    unsigned short* __restrict__ wqkvt, unsigned short* __restrict__ wot,
    unsigned short* __restrict__ hsb) {
  const int i = blockIdx.x;
  const int tx = threadIdx.x, ty = threadIdx.y;
  if (i >= 6144) {                           // hs convert: 1024 blocks x 4096 elems
    const int t = ty*32 + tx;
    const size_t base = (size_t)(i - 6144) * 1024;   // in float4 units
#pragma unroll
    for (int j = 0; j < 4; ++j) {
      const size_t idx = base + j*256 + t;
      float4 v = ((const float4*)hs)[idx];
      ushort4 o;
      o.x = f2bf(v.x); o.y = f2bf(v.y); o.z = f2bf(v.z); o.w = f2bf(v.w);
      ((ushort4*)hsb)[idx] = o;
    }
    return;
  }
  __shared__ float tl[32][33];
  const float* src; unsigned short* dst; int R, C, r0, c0;
  if (i < 2048)      { int l = i;        src = Wq; dst = wqkvt;                      R = 1024; C = 2048; r0 = (l & 31)*32; c0 = (l >> 5)*32; }
  else if (i < 3072) { int l = i - 2048; src = Wk; dst = wqkvt + (size_t)2048*1024;  R = 1024; C = 1024; r0 = (l & 31)*32; c0 = (l >> 5)*32; }
  else if (i < 4096) { int l = i - 3072; src = Wv; dst = wqkvt + (size_t)3072*1024;  R = 1024; C = 1024; r0 = (l & 31)*32; c0 = (l >> 5)*32; }
  else               { int l = i - 4096; src = Wo; dst = wot;                        R = 2048; C = 1024; r0 = (l & 63)*32; c0 = (l >> 6)*32; }
#pragma unroll
  for (int k = 0; k < 4; ++k)
    tl[ty + 8*k][tx] = src[(size_t)(r0 + ty + 8*k)*C + c0 + tx];
  __syncthreads();
#pragma unroll
  for (int k = 0; k < 4; ++k)
    dst[(size_t)(c0 + ty + 8*k)*R + r0 + tx] = f2bf(tl[tx][ty + 8*k]);
}

// -------- QKV GEMM (128x128, BK=64, async dbuf) + fused norm/rope/vtrans --------
// R12: vt8 written in kappa-permuted kv order (within each 64-kv block:
// kv = s2*32 + e2*16 + s1*8 + s0*4 + e1*2 + e0 for slot (slice s, elem e))
// so the attn PV B-fragment (P^T) needs NO cross-lane repack.
__global__ __launch_bounds__(256) void gemm_qkv_fused_kernel(
    const unsigned short* __restrict__ A,      // hs bf16 [4096][1024]
    const unsigned short* __restrict__ Bt,     // wqkvt bf16 [4096][1024]
    const float* __restrict__ qw, const float* __restrict__ kw,
    const int* __restrict__ pos_ids,
    unsigned short* __restrict__ q_l,
    unsigned short* __restrict__ k_l,
    unsigned short* __restrict__ vt8) {
  constexpr int BM = 128, BK = 64, K = 1024, NIT = K/BK;
  __shared__ __align__(16) char smem[70144];   // 68.5 KB -> 2 blocks/CU
  unsigned short* As0 = (unsigned short*)smem;           // 2 x 16 KB
  unsigned short* Bs0 = (unsigned short*)(smem + 32768); // 2 x 16 KB
  float* ftile = (float*)smem;                           // 128 x 136 fp32 (68 KB)
  float* rinv  = (float*)(smem + 69632);                 // 128 fp32

  const int t = threadIdx.x, lane = t & 63, w = t >> 6;
  const int l15 = lane & 15, l4 = lane >> 4;
  const int wr = (w >> 1)*64, wc = (w & 1)*64;
  const int m0 = blockIdx.x * BM, n0 = blockIdx.y * 128;
  const unsigned short* Ab = A + (size_t)m0*K;
  const unsigned short* Bb = Bt + (size_t)n0*K;

  const f32x4 vzero = {0.f, 0.f, 0.f, 0.f};
  f32x4 acc[4][4];
#pragma unroll
  for (int i = 0; i < 4; ++i)
#pragma unroll
    for (int j = 0; j < 4; ++j) acc[i][j] = vzero;

#pragma unroll
  for (int i = 0; i < 4; ++i) {
    const int c = (w*4 + i)*64 + lane;
    glds16(Ab + (size_t)(c >> 3)*K + (c & 7)*8, As0 + (size_t)(w*4 + i)*512);
  }
#pragma unroll
  for (int i = 0; i < 4; ++i) {
    const int c = (w*4 + i)*64 + lane;
    glds16(Bb + (size_t)(c >> 3)*K + (c & 7)*8, Bs0 + (size_t)(w*4 + i)*512);
  }

  for (int kb = 0; kb < NIT; ++kb) {
    const int cur = kb & 1;
    WAIT_LGKM0(); BARRIER();
    if (kb + 1 < NIT) {
      const int kn = (kb + 1) * BK;
      const int nb = (cur^1)*8192;
#pragma unroll
      for (int i = 0; i < 4; ++i) {
        const int c = (w*4 + i)*64 + lane;
        glds16(Ab + (size_t)(c >> 3)*K + kn + (c & 7)*8, As0 + nb + (size_t)(w*4 + i)*512);
      }
#pragma unroll
      for (int i = 0; i < 4; ++i) {
        const int c = (w*4 + i)*64 + lane;
        glds16(Bb + (size_t)(c >> 3)*K + kn + (c & 7)*8, Bs0 + nb + (size_t)(w*4 + i)*512);
      }
      WAIT_VM8();
    } else {
      WAIT_VM0();
    }
    BARRIER();

    const unsigned short* Ac = As0 + cur*8192;
    const unsigned short* Bc = Bs0 + cur*8192;
#pragma unroll
    for (int kk = 0; kk < 2; ++kk) {
      const int kc = kk*4 + l4;
      bf16x8 af[4], bfr[4];
#pragma unroll
      for (int i = 0; i < 4; ++i) {
        int m = wr + i*16 + l15;
        af[i] = *(const bf16x8*)(Ac + ((size_t)m*8 + kc)*8);
      }
#pragma unroll
      for (int j = 0; j < 4; ++j) {
        int n = wc + j*16 + l15;
        bfr[j] = *(const bf16x8*)(Bc + ((size_t)n*8 + kc)*8);
      }
#pragma unroll
      for (int i = 0; i < 4; ++i)
#pragma unroll
        for (int j = 0; j < 4; ++j)
          acc[i][j] = __builtin_amdgcn_mfma_f32_16x16x32_bf16(af[i], bfr[j], acc[i][j], 0, 0, 0);
    }
  }

  // ---- epilogue: spill C-tile to LDS fp32 [128][136] ----
  WAIT_LGKM0(); BARRIER();
#pragma unroll
  for (int i = 0; i < 4; ++i)
#pragma unroll
    for (int j = 0; j < 4; ++j)
#pragma unroll
      for (int r = 0; r < 4; ++r) {
        const int row = wr + i*16 + l4*4 + r;
        const int col = wc + j*16 + l15;
        ftile[row*136 + col] = acc[i][j][r];
      }
  WAIT_LGKM0(); BARRIER();

  const int ny = n0 >> 7;                    // 0..15 q-head, 16..23 k-head, 24..31 v-head
  const int S0 = m0 & (SEQ-1);
  const int bb = m0 >> 11;

  if (ny < 24) {
    const bool isQ = ny < 16;
    {
      const int row = t >> 1, h2 = t & 1;
      const float* fr = ftile + row*136 + h2*64;
      float ssq = 0.f;
#pragma unroll
      for (int c = 0; c < 16; ++c) {
        float4 v = *(const float4*)(fr + 4*c);
        ssq += v.x*v.x + v.y*v.y + v.z*v.z + v.w*v.w;
      }
      ssq = dpp_addx1(ssq);
      if (h2 == 0) rinv[row] = rsqrtf(ssq*(1.0f/128.0f) + 1e-6f);
    }
    WAIT_LGKM0(); BARRIER();
    const float* wgt = isQ ? qw : kw;
    const int d = t & 127, rh = t >> 7;
    const float wd = wgt[d];
    const float w2 = wgt[d ^ 64];
    const float sgn = (d < 64) ? -1.f : 1.f;
    const float sOut = isQ ? 0.12751744f : 1.f;     // (1/sqrt(128))*log2(e) folded into q
    const float invf = exp2f(-(float)(d & 63) * 0.31143075889569023f);
    const int pos0 = pos_ids[S0 + rh*64];
    float cs, sn, dc, dsn;
    __sincosf((float)pos0 * invf, &sn, &cs);
    __sincosf(invf, &dsn, &dc);
    const int head = isQ ? ny : (ny - 16);
    unsigned short* dstb = isQ ? (q_l + ((size_t)(bb*NH + head)*SEQ + S0)*HD)
                               : (k_l + ((size_t)(bb*NKV + head)*SEQ + S0)*HD);
#pragma unroll 4
    for (int k = 0; k < 64; ++k) {
      const int row = rh*64 + k;
      const float r  = rinv[row];
      const float x1 = ftile[row*136 + d];
      const float x2 = ftile[row*136 + (d ^ 64)];
      const float y1 = x1*r*wd, y2 = x2*r*w2;
      const float o  = (y1*cs + sgn*(y2*sn)) * sOut;
      dstb[(size_t)row*HD + d] = f2bf(o);
      const float c2 = cs*dc - sn*dsn;       // rotate: pos -> pos+1
      sn = sn*dc + cs*dsn; cs = c2;
    }
  } else {
    // V-epilogue: kappa-permuted store. Slot (slice sl, elem s8) holds
    // C-row = blk*64 + s2*32 + e2*16 + s1*8 + s0*4 + e1*2 + e0.
    const int vh = ny - 24;
    unsigned short* vb = vt8 + (size_t)(bb*NKV + vh)*HD*SEQ;
    const int d = t & 127, sbh = t >> 7;
#pragma unroll
    for (int sb = 0; sb < 8; ++sb) {
      const int sl = sbh*8 + sb;
      const int blk = sl >> 3, s = sl & 7;
      const int base_r = blk*64 + ((s>>2)<<5) + (((s>>1)&1)<<3) + ((s&1)<<2);
      union { unsigned short u[8]; uint4 q; } pk;
#pragma unroll
      for (int s8 = 0; s8 < 8; ++s8) {
        const int row = base_r + ((s8>>2)<<4) + (((s8>>1)&1)<<1) + (s8&1);
        pk.u[s8] = f2bf(ftile[row*136 + d]);
      }
      *(uint4*)(vb + ((size_t)((S0 >> 3) + sl)*128 + d)*8) = pk.q;
    }
  }
}

// ------------- bf16 GEMM (out-proj): 128x128 tile, fp32 out -------------
__global__ __launch_bounds__(256) void gemm_out_kernel(
    const unsigned short* __restrict__ A,
    const unsigned short* __restrict__ Bt,
    float* __restrict__ Cout, int M, int N, int K) {
  constexpr int BK = 64;
  __shared__ unsigned short As[2][128*BK];   // 2 x 16 KB
  __shared__ unsigned short Bs[2][128*BK];   // 2 x 16 KB  -> 64 KB, 2 blocks/CU
  const int t = threadIdx.x, lane = t & 63, w = t >> 6;
  const int l15 = lane & 15, l4 = lane >> 4;
  const int wr = (w >> 1)*64, wc = (w & 1)*64;
  const int m0 = blockIdx.y * 128, n0 = blockIdx.x * 128;
  const unsigned short* Ab = A + (size_t)m0*K;
  const unsigned short* Bb = Bt + (size_t)n0*K;

  const f32x4 vzero = {0.f, 0.f, 0.f, 0.f};
  f32x4 acc[4][4];
#pragma unroll
  for (int i = 0; i < 4; ++i)
#pragma unroll
    for (int j = 0; j < 4; ++j) acc[i][j] = vzero;

  const int NIT = K / BK;
#pragma unroll
  for (int i = 0; i < 4; ++i) {
    const int c = (w*4 + i)*64 + lane;
    glds16(Ab + (size_t)(c >> 3)*K + (c & 7)*8, &As[0][(size_t)(w*4 + i)*512]);
  }
#pragma unroll
  for (int i = 0; i < 4; ++i) {
    const int c = (w*4 + i)*64 + lane;
    glds16(Bb + (size_t)(c >> 3)*K + (c & 7)*8, &Bs[0][(size_t)(w*4 + i)*512]);
  }

  for (int kb = 0; kb < NIT; ++kb) {
    const int cur = kb & 1;
    WAIT_LGKM0(); BARRIER();
    if (kb + 1 < NIT) {
      const int kn = (kb + 1) * BK;
#pragma unroll
      for (int i = 0; i < 4; ++i) {
        const int c = (w*4 + i)*64 + lane;
        glds16(Ab + (size_t)(c >> 3)*K + kn + (c & 7)*8, &As[cur^1][(size_t)(w*4 + i)*512]);
      }
#pragma unroll
      for (int i = 0; i < 4; ++i) {
        const int c = (w*4 + i)*64 + lane;
        glds16(Bb + (size_t)(c >> 3)*K + kn + (c & 7)*8, &Bs[cur^1][(size_t)(w*4 + i)*512]);
      }
      WAIT_VM8();
    } else {
      WAIT_VM0();
    }
    BARRIER();

#pragma unroll
    for (int kk = 0; kk < 2; ++kk) {
      const int kc = kk*4 + l4;
      bf16x8 af[4], bfr[4];
#pragma unroll
      for (int i = 0; i < 4; ++i) {
        int m = wr + i*16 + l15;
        af[i] = *(const bf16x8*)(&As[cur][((size_t)m*8 + kc)*8]);
      }
#pragma unroll
      for (int j = 0; j < 4; ++j) {
        int n = wc + j*16 + l15;
        bfr[j] = *(const bf16x8*)(&Bs[cur][((size_t)n*8 + kc)*8]);
      }
#pragma unroll
      for (int i = 0; i < 4; ++i)
#pragma unroll
        for (int j = 0; j < 4; ++j)
          acc[i][j] = __builtin_amdgcn_mfma_f32_16x16x32_bf16(af[i], bfr[j], acc[i][j], 0, 0, 0);
    }
  }
#pragma unroll
  for (int i = 0; i < 4; ++i)
#pragma unroll
    for (int j = 0; j < 4; ++j)
#pragma unroll
      for (int r = 0; r < 4; ++r) {
        int row = m0 + wr + i*16 + l4*4 + r;
        int col = n0 + wc + j*16 + l15;
        Cout[(size_t)row*N + col] = acc[i][j][r];
      }
}

// ------------- Flash attention, causal, GQA, KV-SPLIT -------------
// R12: swapped QK^T (S^T = mfma(K,Q)) + kappa-permuted vt8 -> in-register P.
// R13: XCD-clustered 1-D grid. R12's FETCH exploded 31.5->210 MB (L2 streaming
// cliff: round-robin block->XCD put ~16 distinct 1-MB K/V streams on each 4-MB
// L2). Cluster 4 consecutive hb per XCD -> 2 (b,kvh) streams = 2 MB per XCD:
// the ENTIRE K/V stream is L2-resident, reuse no longer depends on block
// lockstep. lid = y*32 + q*8 + xcd (bijective), y ascending keeps LPT.
__global__ __launch_bounds__(256, 3) void attn_kernel(
    const unsigned short* __restrict__ q_l,
    const unsigned short* __restrict__ k_l,
    const unsigned short* __restrict__ vt8,
    unsigned short* __restrict__ o_part,   // [2][B][NH][SEQ][HD] bf16
    float* __restrict__ l_part) {          // [2][B][NH][SEQ] fp32
  __shared__ __align__(16) char smem[49152];
  unsigned short* Ks0 = (unsigned short*)smem;            // 2 x 16 KB dbuf
  unsigned short* Vts = (unsigned short*)(smem + 32768);  // 16 KB single

  const int t = threadIdx.x;
  const int lane = t & 63;
  const int w = t >> 6;
  const int l15 = lane & 15, l4 = lane >> 4;
  const int lid = blockIdx.x;                // 0..1023, 1-D XCD-clustered
  const int hb = (lid & 7)*4 + ((lid >> 3) & 3);  // 4 consecutive hb per XCD
  const int y  = lid >> 5;                   // 0..31, ascending = LPT
  const int h = hb & 15, b = hb >> 4;
  const int qt = 15 - (y >> 1);              // longest first
  const int half = y & 1;
  const int kvh = h >> 1;
  const int q0 = qt * 128;
  const int kt0 = half ? (qt + 1) : 0;
  const int kt1 = half ? (2*qt + 2) : (qt + 1);

  const unsigned short* Kg = k_l + ((size_t)(b*NKV + kvh)*SEQ)*HD;
  const unsigned short* Vg = vt8 + (size_t)(b*NKV + kvh)*HD*SEQ;
  const unsigned short* Qbase = q_l + ((size_t)(b*NH + h)*SEQ)*HD;

  const f32x4 vzero = {0.f,0.f,0.f,0.f};

  // Q fragments in registers (already scaled by 1/sqrt(d)*log2e)
  bf16x8 qf[2][4];
#pragma unroll
  for (int i = 0; i < 2; ++i) {
    const int row = q0 + w*32 + i*16 + l15;
    const unsigned short* Qp = Qbase + (size_t)row*HD;
#pragma unroll
    for (int kk = 0; kk < 4; ++kk)
      qf[i][kk] = *(const bf16x8*)(Qp + kk*32 + l4*8);
  }

  f32x4 oacc[2][8];                          // O^T: [q-subtile][d-tile]
#pragma unroll
  for (int i = 0; i < 2; ++i)
#pragma unroll
    for (int jd = 0; jd < 8; ++jd) oacc[i][jd] = vzero;
  float lrun[2] = {0.f, 0.f};                // per-lane partial row sums

  // prologue: issue K(kt0) into buf 0
  {
    const int k00 = kt0 * 64;
#pragma unroll
    for (int i = 0; i < 4; ++i) {
      const int kc = w*4 + i;
      const int m = lane ^ (kc & 7);
      glds16(Kg + (size_t)(k00 + m)*HD + kc*8, Ks0 + (size_t)kc*64*8);
    }
  }

#pragma unroll 1
  for (int kt = kt0; kt < kt1; ++kt) {
    const int cur = (kt - kt0) & 1;
    const int k0 = kt * 64;
    // own K(kt) loads landed; barrier => all waves' K(kt) staged AND
    // all waves finished PV(kt-1) reads of the single V buffer.
    WAIT_VM0(); BARRIER();

    // issue V(kt) (4/wave, first) then K(kt+1) (4/wave) -> counted waits
#pragma unroll
    for (int i = 0; i < 4; ++i) {
      const int id = w*4 + i;
      const int skc = id >> 1, hh = id & 1;
      const int d = (hh*64 + lane) ^ skc;
      glds16(Vg + ((size_t)((k0 >> 3) + skc)*128 + d)*8, Vts + (size_t)(skc*128 + hh*64)*8);
    }
    const bool pk_ = (kt + 1 < kt1);
    if (pk_) {
      const int kn = k0 + 64;
      unsigned short* Ksn = Ks0 + (cur^1)*8192;
#pragma unroll
      for (int i = 0; i < 4; ++i) {
        const int kc = w*4 + i;
        const int m = lane ^ (kc & 7);
        glds16(Kg + (size_t)(kn + m)*HD + kc*8, Ksn + (size_t)kc*64*8);
      }
    }

    const unsigned short* KsC = Ks0 + cur*8192;

    // S^T = K Q^T (lane: q = l15 within subtile, kv = j*16 + l4*4 + r)
    f32x4 sacc[4][2];
#pragma unroll
    for (int j = 0; j < 4; ++j)
#pragma unroll
      for (int i = 0; i < 2; ++i) sacc[j][i] = vzero;
    __builtin_amdgcn_s_setprio(1);
#pragma unroll
    for (int kk = 0; kk < 4; ++kk) {
      const int kc = kk*4 + l4;
      bf16x8 kb[4];
#pragma unroll
      for (int j = 0; j < 4; ++j) {
        int n = j*16 + l15;
        kb[j] = *(const bf16x8*)(KsC + ((size_t)kc*64 + (n ^ (kc & 7)))*8);
      }
#pragma unroll
      for (int j = 0; j < 4; ++j)
#pragma unroll
        for (int i = 0; i < 2; ++i)
          sacc[j][i] = __builtin_amdgcn_mfma_f32_16x16x32_bf16(kb[j], qf[i][kk], sacc[j][i], 0,0,0);
    }
    __builtin_amdgcn_s_setprio(0);

    // P = exp2(S) (no max); causal mask on the diag tiles
    const bool diag = (kt >= 2*qt);
#pragma unroll
    for (int j = 0; j < 4; ++j)
#pragma unroll
      for (int i = 0; i < 2; ++i)
#pragma unroll
        for (int r = 0; r < 4; ++r) {
          float sv = sacc[j][i][r];
          if (diag) {
            const int kvg = k0 + j*16 + l4*4 + r;
            const int qg  = q0 + w*32 + i*16 + l15;
            sv = (kvg > qg) ? -INFINITY : sv;
          }
          float pv = EXP2(sv);
          sacc[j][i][r] = pv;
          lrun[i] += pv;
        }

    // V(kt) staged by all waves (keep K(kt+1) in flight)
    if (pk_) { WAIT_VM4(); } else { WAIT_VM0(); }
    BARRIER();

    // O^T += V^T P^T  (A = V^T frag from LDS, B = own packed P)
#pragma unroll
    for (int kk = 0; kk < 2; ++kk) {
      union { unsigned int u[4]; bf16x8 v; } pb[2];
#pragma unroll
      for (int i = 0; i < 2; ++i) {
        const f32x4 t0 = sacc[kk*2][i], t1 = sacc[kk*2+1][i];
        pb[i].u[0] = (__float_as_uint(t0[0]) >> 16) | (__float_as_uint(t0[1]) & 0xFFFF0000u);
        pb[i].u[1] = (__float_as_uint(t0[2]) >> 16) | (__float_as_uint(t0[3]) & 0xFFFF0000u);
        pb[i].u[2] = (__float_as_uint(t1[0]) >> 16) | (__float_as_uint(t1[1]) & 0xFFFF0000u);
        pb[i].u[3] = (__float_as_uint(t1[2]) >> 16) | (__float_as_uint(t1[3]) & 0xFFFF0000u);
      }
      const int s = kk*4 + l4;
      __builtin_amdgcn_s_setprio(1);
#pragma unroll
      for (int td = 0; td < 8; ++td) {
        const int dd = td*16 + l15;
        bf16x8 va = *(const bf16x8*)(Vts + ((size_t)s*128 + (dd ^ s))*8);
#pragma unroll
        for (int i = 0; i < 2; ++i)
          oacc[i][td] = __builtin_amdgcn_mfma_f32_16x16x32_bf16(va, pb[i].v, oacc[i][td], 0,0,0);
      }
      __builtin_amdgcn_s_setprio(0);
    }
  }

  // epilogue: reduce lrun across the 4 l4-groups, normalize, store O^T.
  unsigned short* ob = o_part + ((size_t)half*BATCH*NH*SEQ + (size_t)(b*NH + h)*SEQ)*HD;
  float* lb = l_part + (size_t)half*BATCH*NH*SEQ + (size_t)(b*NH + h)*SEQ;
#pragma unroll
  for (int i = 0; i < 2; ++i) {
    float lsum = lrun[i];
    lsum += __shfl_xor(lsum, 16, 64);
    lsum += __shfl_xor(lsum, 32, 64);
    const float inv = (lsum > 0.f) ? 1.0f / lsum : 0.f;
    const int row = q0 + w*32 + i*16 + l15;
    if (l4 == 0) lb[row] = lsum;
#pragma unroll
    for (int td = 0; td < 8; ++td) {
      union { unsigned int u[2]; uint2 q; } pk;
      const float v0 = oacc[i][td][0]*inv, v1 = oacc[i][td][1]*inv;
      const float v2 = oacc[i][td][2]*inv, v3 = oacc[i][td][3]*inv;
      pk.u[0] = (unsigned int)f2bf(v0) | ((unsigned int)f2bf(v1) << 16);
      pk.u[1] = (unsigned int)f2bf(v2) | ((unsigned int)f2bf(v3) << 16);
      *(uint2*)(ob + (size_t)row*HD + td*16 + l4*4) = pk.q;
    }
  }
}

// ------------- combine: attn_o = (la*Oa + lb*Ob) / (la+lb) -------------
__global__ __launch_bounds__(256) void combine_kernel(
    const unsigned short* __restrict__ o_part,  // [2][B*NH*SEQ][HD] bf16
    const float* __restrict__ l_part,           // [2][B*NH*SEQ] fp32
    unsigned short* __restrict__ attn_o) {      // [B][SEQ][NH*HD] bf16
  const int tid = blockIdx.x * 256 + threadIdx.x;  // 1,048,576 threads
  const int d8 = tid & 15;                    // 16 chunks of 8 d
  const int row = tid >> 4;                   // (b*NH+h)*SEQ + s
  const int s = row & (SEQ-1);
  const int bh = row >> 11;
  const int h = bh & 15, b = bh >> 4;
  const float la = l_part[row];
  const float lbv = l_part[BATCH*NH*SEQ + row];
  const float inv = 1.f / (la + lbv);
  const float wa = la * inv, wb = lbv * inv;
  const unsigned short* pa = o_part + (size_t)row*HD + d8*8;
  const unsigned short* pb = pa + (size_t)BATCH*NH*SEQ*HD;
  uint4 ua = *(const uint4*)pa;
  uint4 ub = *(const uint4*)pb;
  const unsigned short* ea = (const unsigned short*)&ua;
  const unsigned short* eb = (const unsigned short*)&ub;
  union { unsigned short u[8]; uint4 q; } o;
#pragma unroll
  for (int k = 0; k < 8; ++k)
    o.u[k] = f2bf(bf2f(ea[k])*wa + bf2f(eb[k])*wb);
  *(uint4*)(attn_o + ((size_t)(b*SEQ + s)*(NH*HD)) + h*HD + d8*8) = o.q;
}

extern "C" void kernel_launch(void* const* d_in, const int* in_sizes, int n_in,
                              void* d_out, int out_size, void* d_ws, size_t ws_size,
                              hipStream_t stream) {
  const float* hs = (const float*)d_in[0];
  const int* pos  = (const int*)d_in[1];
  const float* Wq = (const float*)d_in[2];
  const float* Wk = (const float*)d_in[3];
  const float* Wv = (const float*)d_in[4];
  const float* Wo = (const float*)d_in[5];
  const float* qw = (const float*)d_in[6];
  const float* kw = (const float*)d_in[7];
  float* out = (float*)d_out;
  char* ws = (char*)d_ws;

  unsigned short* attn_o = (unsigned short*)(ws + 0);                    // 16 MB
  unsigned short* wot    = (unsigned short*)(ws + ((size_t)16 << 20));   // 4 MB
  unsigned short* q_l    = (unsigned short*)(ws + ((size_t)20 << 20));   // 16 MB
  unsigned short* k_l    = (unsigned short*)(ws + ((size_t)36 << 20));   // 8 MB
  unsigned short* vt8    = (unsigned short*)(ws + ((size_t)44 << 20));   // 8 MB
  unsigned short* o_part = (unsigned short*)(ws + ((size_t)52 << 20));   // 32 MB
  unsigned short* hsb    = (unsigned short*)(ws + ((size_t)52 << 20));   // 8 MB (alias)
  unsigned short* wqkvt  = (unsigned short*)(ws + ((size_t)60 << 20));   // 8 MB (alias)
  float*          l_part = (float*)(ws + ((size_t)84 << 20));            // 512 KB

  // 1. all converts in one launch (weights transpose-convert + hs convert)
  tcvt_all_kernel<<<dim3(7168), dim3(32, 8), 0, stream>>>(Wq, Wk, Wv, Wo, hs, wqkvt, wot, hsb);
  // 2. QKV projection + fused RMSNorm/RoPE/V-transpose epilogue (kappa-permuted vt8)
  gemm_qkv_fused_kernel<<<dim3(32, 32), dim3(256), 0, stream>>>(hsb, wqkvt, qw, kw, pos, q_l, k_l, vt8);
  // 3. flash attention, swapped-QK^T + in-register P, XCD-clustered 1-D grid
  attn_kernel<<<dim3(1024), dim3(256), 0, stream>>>(q_l, k_l, vt8, o_part, l_part);
  // 3b. combine partials -> attn_o
  combine_kernel<<<dim3(4096), dim3(256), 0, stream>>>(o_part, l_part, attn_o);
  // 4. output projection: 128x128 tiles, grid (N/128=8, M/128=32) = 256 blocks
  gemm_out_kernel<<<dim3(8, 32), dim3(256), 0, stream>>>(attn_o, wot, out, 4096, 1024, 2048);
}

// Round 8
// 258.210 us; speedup vs baseline: 1.3895x; 1.3670x over previous
//
#include <hip/hip_runtime.h>
#include <cstdint>
#include <cstddef>

#define HIDDEN 1024
#define NH 16
#define NKV 8
#define HD 128
#define SEQ 2048
#define BATCH 2
#define NTOK (BATCH*SEQ)        /* 4096 */

typedef __bf16 bf16x8 __attribute__((ext_vector_type(8)));
typedef float f32x4 __attribute__((ext_vector_type(4)));

__device__ __forceinline__ unsigned short f2bf(float f) {
  unsigned int u = __float_as_uint(f);
  u += 0x7FFFu + ((u >> 16) & 1u);          // round-to-nearest-even
  return (unsigned short)(u >> 16);
}
__device__ __forceinline__ float bf2f(unsigned short h) {
  return __uint_as_float(((unsigned int)h) << 16);
}

#if __has_builtin(__builtin_amdgcn_exp2f)
#define EXP2(x) __builtin_amdgcn_exp2f(x)
#else
#define EXP2(x) exp2f(x)
#endif

// async global->LDS, 16B per lane; LDS dest = uniform base + lane*16
__device__ __forceinline__ void glds16(const unsigned short* g, unsigned short* l) {
  __builtin_amdgcn_global_load_lds(
      (const __attribute__((address_space(1))) unsigned int*)g,
      (__attribute__((address_space(3))) unsigned int*)l, 16, 0, 0);
}

// s_waitcnt immediates (gfx9/CDNA: vmcnt[3:0]+[15:14], exp[6:4], lgkm[11:8])
#define WAIT_VM8()   __builtin_amdgcn_s_waitcnt(0x0F78)  /* vmcnt<=8 */
#define WAIT_VM6()   __builtin_amdgcn_s_waitcnt(0x0F76)  /* vmcnt<=6 */
#define WAIT_VM4()   __builtin_amdgcn_s_waitcnt(0x0F74)  /* vmcnt<=4 */
#define WAIT_VM0()   __builtin_amdgcn_s_waitcnt(0x0F70)  /* vmcnt<=0 */
#define WAIT_LGKM0() __builtin_amdgcn_s_waitcnt(0xC07F)  /* lgkmcnt<=0 */
#define BARRIER()    __builtin_amdgcn_s_barrier()

// adjacent-lane (xor 1) exchange-add via quad_perm [1,0,3,2]
__device__ __forceinline__ float dpp_addx1(float x) {
  int v = __builtin_amdgcn_update_dpp(0, __float_as_int(x), 0xB1, 0xF, 0xF, true);
  return x + __int_as_float(v);
}

// ---- all-weights transpose-convert + hs convert, ONE launch ----
__global__ __launch_bounds__(256) void tcvt_all_kernel(
    const float* __restrict__ Wq, const float* __restrict__ Wk,
    const float* __restrict__ Wv, const float* __restrict__ Wo,
    const float* __restrict__ hs,
    unsigned short* __restrict__ wqkvt, unsigned short* __restrict__ wot,
    unsigned short* __restrict__ hsb) {
  const int i = blockIdx.x;
  const int tx = threadIdx.x, ty = threadIdx.y;
  if (i >= 6144) {                           // hs convert: 1024 blocks x 4096 elems
    const int t = ty*32 + tx;
    const size_t base = (size_t)(i - 6144) * 1024;   // in float4 units
#pragma unroll
    for (int j = 0; j < 4; ++j) {
      const size_t idx = base + j*256 + t;
      float4 v = ((const float4*)hs)[idx];
      ushort4 o;
      o.x = f2bf(v.x); o.y = f2bf(v.y); o.z = f2bf(v.z); o.w = f2bf(v.w);
      ((ushort4*)hsb)[idx] = o;
    }
    return;
  }
  __shared__ float tl[32][33];
  const float* src; unsigned short* dst; int R, C, r0, c0;
  if (i < 2048)      { int l = i;        src = Wq; dst = wqkvt;                      R = 1024; C = 2048; r0 = (l & 31)*32; c0 = (l >> 5)*32; }
  else if (i < 3072) { int l = i - 2048; src = Wk; dst = wqkvt + (size_t)2048*1024;  R = 1024; C = 1024; r0 = (l & 31)*32; c0 = (l >> 5)*32; }
  else if (i < 4096) { int l = i - 3072; src = Wv; dst = wqkvt + (size_t)3072*1024;  R = 1024; C = 1024; r0 = (l & 31)*32; c0 = (l >> 5)*32; }
  else               { int l = i - 4096; src = Wo; dst = wot;                        R = 2048; C = 1024; r0 = (l & 63)*32; c0 = (l >> 6)*32; }
#pragma unroll
  for (int k = 0; k < 4; ++k)
    tl[ty + 8*k][tx] = src[(size_t)(r0 + ty + 8*k)*C + c0 + tx];
  __syncthreads();
#pragma unroll
  for (int k = 0; k < 4; ++k)
    dst[(size_t)(c0 + ty + 8*k)*R + r0 + tx] = f2bf(tl[tx][ty + 8*k]);
}

// -------- QKV GEMM (128x128, BK=64, async dbuf) + fused norm/rope/vtrans --------
// R12: vt8 written in kappa-permuted kv order (within each 64-kv block:
// kv = s2*32 + e2*16 + s1*8 + s0*4 + e1*2 + e0 for slot (slice s, elem e))
// so the attn PV B-fragment (P^T) needs NO cross-lane repack.
__global__ __launch_bounds__(256) void gemm_qkv_fused_kernel(
    const unsigned short* __restrict__ A,      // hs bf16 [4096][1024]
    const unsigned short* __restrict__ Bt,     // wqkvt bf16 [4096][1024]
    const float* __restrict__ qw, const float* __restrict__ kw,
    const int* __restrict__ pos_ids,
    unsigned short* __restrict__ q_l,
    unsigned short* __restrict__ k_l,
    unsigned short* __restrict__ vt8) {
  constexpr int BM = 128, BK = 64, K = 1024, NIT = K/BK;
  __shared__ __align__(16) char smem[70144];   // 68.5 KB -> 2 blocks/CU
  unsigned short* As0 = (unsigned short*)smem;           // 2 x 16 KB
  unsigned short* Bs0 = (unsigned short*)(smem + 32768); // 2 x 16 KB
  float* ftile = (float*)smem;                           // 128 x 136 fp32 (68 KB)
  float* rinv  = (float*)(smem + 69632);                 // 128 fp32

  const int t = threadIdx.x, lane = t & 63, w = t >> 6;
  const int l15 = lane & 15, l4 = lane >> 4;
  const int wr = (w >> 1)*64, wc = (w & 1)*64;
  const int m0 = blockIdx.x * BM, n0 = blockIdx.y * 128;
  const unsigned short* Ab = A + (size_t)m0*K;
  const unsigned short* Bb = Bt + (size_t)n0*K;

  const f32x4 vzero = {0.f, 0.f, 0.f, 0.f};
  f32x4 acc[4][4];
#pragma unroll
  for (int i = 0; i < 4; ++i)
#pragma unroll
    for (int j = 0; j < 4; ++j) acc[i][j] = vzero;

#pragma unroll
  for (int i = 0; i < 4; ++i) {
    const int c = (w*4 + i)*64 + lane;
    glds16(Ab + (size_t)(c >> 3)*K + (c & 7)*8, As0 + (size_t)(w*4 + i)*512);
  }
#pragma unroll
  for (int i = 0; i < 4; ++i) {
    const int c = (w*4 + i)*64 + lane;
    glds16(Bb + (size_t)(c >> 3)*K + (c & 7)*8, Bs0 + (size_t)(w*4 + i)*512);
  }

  for (int kb = 0; kb < NIT; ++kb) {
    const int cur = kb & 1;
    WAIT_LGKM0(); BARRIER();
    if (kb + 1 < NIT) {
      const int kn = (kb + 1) * BK;
      const int nb = (cur^1)*8192;
#pragma unroll
      for (int i = 0; i < 4; ++i) {
        const int c = (w*4 + i)*64 + lane;
        glds16(Ab + (size_t)(c >> 3)*K + kn + (c & 7)*8, As0 + nb + (size_t)(w*4 + i)*512);
      }
#pragma unroll
      for (int i = 0; i < 4; ++i) {
        const int c = (w*4 + i)*64 + lane;
        glds16(Bb + (size_t)(c >> 3)*K + kn + (c & 7)*8, Bs0 + nb + (size_t)(w*4 + i)*512);
      }
      WAIT_VM8();
    } else {
      WAIT_VM0();
    }
    BARRIER();

    const unsigned short* Ac = As0 + cur*8192;
    const unsigned short* Bc = Bs0 + cur*8192;
#pragma unroll
    for (int kk = 0; kk < 2; ++kk) {
      const int kc = kk*4 + l4;
      bf16x8 af[4], bfr[4];
#pragma unroll
      for (int i = 0; i < 4; ++i) {
        int m = wr + i*16 + l15;
        af[i] = *(const bf16x8*)(Ac + ((size_t)m*8 + kc)*8);
      }
#pragma unroll
      for (int j = 0; j < 4; ++j) {
        int n = wc + j*16 + l15;
        bfr[j] = *(const bf16x8*)(Bc + ((size_t)n*8 + kc)*8);
      }
#pragma unroll
      for (int i = 0; i < 4; ++i)
#pragma unroll
        for (int j = 0; j < 4; ++j)
          acc[i][j] = __builtin_amdgcn_mfma_f32_16x16x32_bf16(af[i], bfr[j], acc[i][j], 0, 0, 0);
    }
  }

  // ---- epilogue: spill C-tile to LDS fp32 [128][136] ----
  WAIT_LGKM0(); BARRIER();
#pragma unroll
  for (int i = 0; i < 4; ++i)
#pragma unroll
    for (int j = 0; j < 4; ++j)
#pragma unroll
      for (int r = 0; r < 4; ++r) {
        const int row = wr + i*16 + l4*4 + r;
        const int col = wc + j*16 + l15;
        ftile[row*136 + col] = acc[i][j][r];
      }
  WAIT_LGKM0(); BARRIER();

  const int ny = n0 >> 7;                    // 0..15 q-head, 16..23 k-head, 24..31 v-head
  const int S0 = m0 & (SEQ-1);
  const int bb = m0 >> 11;

  if (ny < 24) {
    const bool isQ = ny < 16;
    {
      const int row = t >> 1, h2 = t & 1;
      const float* fr = ftile + row*136 + h2*64;
      float ssq = 0.f;
#pragma unroll
      for (int c = 0; c < 16; ++c) {
        float4 v = *(const float4*)(fr + 4*c);
        ssq += v.x*v.x + v.y*v.y + v.z*v.z + v.w*v.w;
      }
      ssq = dpp_addx1(ssq);
      if (h2 == 0) rinv[row] = rsqrtf(ssq*(1.0f/128.0f) + 1e-6f);
    }
    WAIT_LGKM0(); BARRIER();
    const float* wgt = isQ ? qw : kw;
    const int d = t & 127, rh = t >> 7;
    const float wd = wgt[d];
    const float w2 = wgt[d ^ 64];
    const float sgn = (d < 64) ? -1.f : 1.f;
    const float sOut = isQ ? 0.12751744f : 1.f;     // (1/sqrt(128))*log2(e) folded into q
    const float invf = exp2f(-(float)(d & 63) * 0.31143075889569023f);
    const int pos0 = pos_ids[S0 + rh*64];
    float cs, sn, dc, dsn;
    __sincosf((float)pos0 * invf, &sn, &cs);
    __sincosf(invf, &dsn, &dc);
    const int head = isQ ? ny : (ny - 16);
    unsigned short* dstb = isQ ? (q_l + ((size_t)(bb*NH + head)*SEQ + S0)*HD)
                               : (k_l + ((size_t)(bb*NKV + head)*SEQ + S0)*HD);
#pragma unroll 4
    for (int k = 0; k < 64; ++k) {
      const int row = rh*64 + k;
      const float r  = rinv[row];
      const float x1 = ftile[row*136 + d];
      const float x2 = ftile[row*136 + (d ^ 64)];
      const float y1 = x1*r*wd, y2 = x2*r*w2;
      const float o  = (y1*cs + sgn*(y2*sn)) * sOut;
      dstb[(size_t)row*HD + d] = f2bf(o);
      const float c2 = cs*dc - sn*dsn;       // rotate: pos -> pos+1
      sn = sn*dc + cs*dsn; cs = c2;
    }
  } else {
    // V-epilogue: kappa-permuted store. Slot (slice sl, elem s8) holds
    // C-row = blk*64 + s2*32 + e2*16 + s1*8 + s0*4 + e1*2 + e0.
    const int vh = ny - 24;
    unsigned short* vb = vt8 + (size_t)(bb*NKV + vh)*HD*SEQ;
    const int d = t & 127, sbh = t >> 7;
#pragma unroll
    for (int sb = 0; sb < 8; ++sb) {
      const int sl = sbh*8 + sb;
      const int blk = sl >> 3, s = sl & 7;
      const int base_r = blk*64 + ((s>>2)<<5) + (((s>>1)&1)<<3) + ((s&1)<<2);
      union { unsigned short u[8]; uint4 q; } pk;
#pragma unroll
      for (int s8 = 0; s8 < 8; ++s8) {
        const int row = base_r + ((s8>>2)<<4) + (((s8>>1)&1)<<1) + (s8&1);
        pk.u[s8] = f2bf(ftile[row*136 + d]);
      }
      *(uint4*)(vb + ((size_t)((S0 >> 3) + sl)*128 + d)*8) = pk.q;
    }
  }
}

// ------------- bf16 GEMM (out-proj): 128x128 tile, fp32 out -------------
__global__ __launch_bounds__(256) void gemm_out_kernel(
    const unsigned short* __restrict__ A,
    const unsigned short* __restrict__ Bt,
    float* __restrict__ Cout, int M, int N, int K) {
  constexpr int BK = 64;
  __shared__ unsigned short As[2][128*BK];   // 2 x 16 KB
  __shared__ unsigned short Bs[2][128*BK];   // 2 x 16 KB  -> 64 KB, 2 blocks/CU
  const int t = threadIdx.x, lane = t & 63, w = t >> 6;
  const int l15 = lane & 15, l4 = lane >> 4;
  const int wr = (w >> 1)*64, wc = (w & 1)*64;
  const int m0 = blockIdx.y * 128, n0 = blockIdx.x * 128;
  const unsigned short* Ab = A + (size_t)m0*K;
  const unsigned short* Bb = Bt + (size_t)n0*K;

  const f32x4 vzero = {0.f, 0.f, 0.f, 0.f};
  f32x4 acc[4][4];
#pragma unroll
  for (int i = 0; i < 4; ++i)
#pragma unroll
    for (int j = 0; j < 4; ++j) acc[i][j] = vzero;

  const int NIT = K / BK;
#pragma unroll
  for (int i = 0; i < 4; ++i) {
    const int c = (w*4 + i)*64 + lane;
    glds16(Ab + (size_t)(c >> 3)*K + (c & 7)*8, &As[0][(size_t)(w*4 + i)*512]);
  }
#pragma unroll
  for (int i = 0; i < 4; ++i) {
    const int c = (w*4 + i)*64 + lane;
    glds16(Bb + (size_t)(c >> 3)*K + (c & 7)*8, &Bs[0][(size_t)(w*4 + i)*512]);
  }

  for (int kb = 0; kb < NIT; ++kb) {
    const int cur = kb & 1;
    WAIT_LGKM0(); BARRIER();
    if (kb + 1 < NIT) {
      const int kn = (kb + 1) * BK;
#pragma unroll
      for (int i = 0; i < 4; ++i) {
        const int c = (w*4 + i)*64 + lane;
        glds16(Ab + (size_t)(c >> 3)*K + kn + (c & 7)*8, &As[cur^1][(size_t)(w*4 + i)*512]);
      }
#pragma unroll
      for (int i = 0; i < 4; ++i) {
        const int c = (w*4 + i)*64 + lane;
        glds16(Bb + (size_t)(c >> 3)*K + kn + (c & 7)*8, &Bs[cur^1][(size_t)(w*4 + i)*512]);
      }
      WAIT_VM8();
    } else {
      WAIT_VM0();
    }
    BARRIER();

#pragma unroll
    for (int kk = 0; kk < 2; ++kk) {
      const int kc = kk*4 + l4;
      bf16x8 af[4], bfr[4];
#pragma unroll
      for (int i = 0; i < 4; ++i) {
        int m = wr + i*16 + l15;
        af[i] = *(const bf16x8*)(&As[cur][((size_t)m*8 + kc)*8]);
      }
#pragma unroll
      for (int j = 0; j < 4; ++j) {
        int n = wc + j*16 + l15;
        bfr[j] = *(const bf16x8*)(&Bs[cur][((size_t)n*8 + kc)*8]);
      }
#pragma unroll
      for (int i = 0; i < 4; ++i)
#pragma unroll
        for (int j = 0; j < 4; ++j)
          acc[i][j] = __builtin_amdgcn_mfma_f32_16x16x32_bf16(af[i], bfr[j], acc[i][j], 0, 0, 0);
    }
  }
#pragma unroll
  for (int i = 0; i < 4; ++i)
#pragma unroll
    for (int j = 0; j < 4; ++j)
#pragma unroll
      for (int r = 0; r < 4; ++r) {
        int row = m0 + wr + i*16 + l4*4 + r;
        int col = n0 + wc + j*16 + l15;
        Cout[(size_t)row*N + col] = acc[i][j][r];
      }
}

// ------------- Flash attention, causal, GQA, KV-SPLIT -------------
// R14: R12's in-register-P datapath (swapped QK^T + kappa-permuted vt8,
// zero LDS traffic for P) grafted back onto R1's PROVEN memory config:
// 2-D grid (hb fast, y slow), K AND V double-buffered (LDS 64 KB -> 2
// blocks/CU), 8 loads/iter with WAIT_VM8 counted prefetch. R12/R13's
// FETCH explosion (210/143 MB vs R1's 31.5 MB compulsory) traced to
// broken temporal lockstep (3 blocks/CU + phase-scattered grids), NOT
// L2 capacity — same-stream blocks must touch K/V tiles close in time.
__global__ __launch_bounds__(256, 2) void attn_kernel(
    const unsigned short* __restrict__ q_l,
    const unsigned short* __restrict__ k_l,
    const unsigned short* __restrict__ vt8,
    unsigned short* __restrict__ o_part,   // [2][B][NH][SEQ][HD] bf16
    float* __restrict__ l_part) {          // [2][B][NH][SEQ] fp32
  __shared__ __align__(16) char smem[65536];
  unsigned short* Ks0  = (unsigned short*)smem;            // 2 x 16 KB dbuf
  unsigned short* Vts0 = (unsigned short*)(smem + 32768);  // 2 x 16 KB dbuf

  const int t = threadIdx.x;
  const int lane = t & 63;
  const int w = t >> 6;
  const int l15 = lane & 15, l4 = lane >> 4;
  const int hb = blockIdx.x;                 // h + 16*b (fast dim: K/V L2 share)
  const int h = hb & 15, b = hb >> 4;
  const int y = blockIdx.y;                  // 0..31
  const int qt = 15 - (y >> 1);              // longest first
  const int half = y & 1;
  const int kvh = h >> 1;
  const int q0 = qt * 128;
  const int kt0 = half ? (qt + 1) : 0;
  const int kt1 = half ? (2*qt + 2) : (qt + 1);

  const unsigned short* Kg = k_l + ((size_t)(b*NKV + kvh)*SEQ)*HD;
  const unsigned short* Vg = vt8 + (size_t)(b*NKV + kvh)*HD*SEQ;
  const unsigned short* Qbase = q_l + ((size_t)(b*NH + h)*SEQ)*HD;

  const f32x4 vzero = {0.f,0.f,0.f,0.f};

  // Q fragments in registers (already scaled by 1/sqrt(d)*log2e)
  bf16x8 qf[2][4];
#pragma unroll
  for (int i = 0; i < 2; ++i) {
    const int row = q0 + w*32 + i*16 + l15;
    const unsigned short* Qp = Qbase + (size_t)row*HD;
#pragma unroll
    for (int kk = 0; kk < 4; ++kk)
      qf[i][kk] = *(const bf16x8*)(Qp + kk*32 + l4*8);
  }

  f32x4 oacc[2][8];                          // O^T: [q-subtile][d-tile]
#pragma unroll
  for (int i = 0; i < 2; ++i)
#pragma unroll
    for (int jd = 0; jd < 8; ++jd) oacc[i][jd] = vzero;
  float lrun[2] = {0.f, 0.f};                // per-lane partial row sums

  // prologue: issue K(kt0)+V(kt0) into buf 0 (8 loads/wave, R1 pattern)
  {
    const int k00 = kt0 * 64;
#pragma unroll
    for (int i = 0; i < 4; ++i) {            // K tile
      const int kc = w*4 + i;
      const int m = lane ^ (kc & 7);
      glds16(Kg + (size_t)(k00 + m)*HD + kc*8, Ks0 + (size_t)kc*64*8);
    }
#pragma unroll
    for (int i = 0; i < 4; ++i) {            // V tile (kappa-permuted vt8)
      const int id = w*4 + i;
      const int skc = id >> 1, hh = id & 1;
      const int d = (hh*64 + lane) ^ skc;
      glds16(Vg + ((size_t)((k00 >> 3) + skc)*128 + d)*8, Vts0 + (size_t)(skc*128 + hh*64)*8);
    }
  }

#pragma unroll 1
  for (int kt = kt0; kt < kt1; ++kt) {
    const int cur = (kt - kt0) & 1;
    const int k0 = kt * 64;
    WAIT_LGKM0(); BARRIER();                 // all waves done reading buf cur^1
    if (kt + 1 < kt1) {                      // prefetch kt+1 into buf cur^1
      const int kn = k0 + 64;
      unsigned short* Ksn  = Ks0  + (cur^1)*8192;
      unsigned short* Vtsn = Vts0 + (cur^1)*8192;
#pragma unroll
      for (int i = 0; i < 4; ++i) {
        const int kc = w*4 + i;
        const int m = lane ^ (kc & 7);
        glds16(Kg + (size_t)(kn + m)*HD + kc*8, Ksn + (size_t)kc*64*8);
      }
#pragma unroll
      for (int i = 0; i < 4; ++i) {
        const int id = w*4 + i;
        const int skc = id >> 1, hh = id & 1;
        const int d = (hh*64 + lane) ^ skc;
        glds16(Vg + ((size_t)((kn >> 3) + skc)*128 + d)*8, Vtsn + (size_t)(skc*128 + hh*64)*8);
      }
      WAIT_VM8();                             // drain only cur's 8 loads
    } else {
      WAIT_VM0();
    }
    BARRIER();                                // buf cur fully staged

    const unsigned short* KsC  = Ks0  + cur*8192;
    const unsigned short* VtsC = Vts0 + cur*8192;

    // S^T = K Q^T (lane: q = l15 within subtile, kv = j*16 + l4*4 + r)
    f32x4 sacc[4][2];
#pragma unroll
    for (int j = 0; j < 4; ++j)
#pragma unroll
      for (int i = 0; i < 2; ++i) sacc[j][i] = vzero;
    __builtin_amdgcn_s_setprio(1);
#pragma unroll
    for (int kk = 0; kk < 4; ++kk) {
      const int kc = kk*4 + l4;
      bf16x8 kb[4];
#pragma unroll
      for (int j = 0; j < 4; ++j) {
        int n = j*16 + l15;
        kb[j] = *(const bf16x8*)(KsC + ((size_t)kc*64 + (n ^ (kc & 7)))*8);
      }
#pragma unroll
      for (int j = 0; j < 4; ++j)
#pragma unroll
        for (int i = 0; i < 2; ++i)
          sacc[j][i] = __builtin_amdgcn_mfma_f32_16x16x32_bf16(kb[j], qf[i][kk], sacc[j][i], 0,0,0);
    }
    __builtin_amdgcn_s_setprio(0);

    // P = exp2(S) (no max); causal mask on the diag tiles
    const bool diag = (kt >= 2*qt);
#pragma unroll
    for (int j = 0; j < 4; ++j)
#pragma unroll
      for (int i = 0; i < 2; ++i)
#pragma unroll
        for (int r = 0; r < 4; ++r) {
          float sv = sacc[j][i][r];
          if (diag) {
            const int kvg = k0 + j*16 + l4*4 + r;
            const int qg  = q0 + w*32 + i*16 + l15;
            sv = (kvg > qg) ? -INFINITY : sv;
          }
          float pv = EXP2(sv);
          sacc[j][i][r] = pv;
          lrun[i] += pv;
        }

    // O^T += V^T P^T  (A = V^T frag from LDS, B = own packed P)
#pragma unroll
    for (int kk = 0; kk < 2; ++kk) {
      union { unsigned int u[4]; bf16x8 v; } pb[2];
#pragma unroll
      for (int i = 0; i < 2; ++i) {
        const f32x4 t0 = sacc[kk*2][i], t1 = sacc[kk*2+1][i];
        pb[i].u[0] = (__float_as_uint(t0[0]) >> 16) | (__float_as_uint(t0[1]) & 0xFFFF0000u);
        pb[i].u[1] = (__float_as_uint(t0[2]) >> 16) | (__float_as_uint(t0[3]) & 0xFFFF0000u);
        pb[i].u[2] = (__float_as_uint(t1[0]) >> 16) | (__float_as_uint(t1[1]) & 0xFFFF0000u);
        pb[i].u[3] = (__float_as_uint(t1[2]) >> 16) | (__float_as_uint(t1[3]) & 0xFFFF0000u);
      }
      const int s = kk*4 + l4;
      __builtin_amdgcn_s_setprio(1);
#pragma unroll
      for (int td = 0; td < 8; ++td) {
        const int dd = td*16 + l15;
        bf16x8 va = *(const bf16x8*)(VtsC + ((size_t)s*128 + (dd ^ s))*8);
#pragma unroll
        for (int i = 0; i < 2; ++i)
          oacc[i][td] = __builtin_amdgcn_mfma_f32_16x16x32_bf16(va, pb[i].v, oacc[i][td], 0,0,0);
      }
      __builtin_amdgcn_s_setprio(0);
    }
  }

  // epilogue: reduce lrun across the 4 l4-groups, normalize, store O^T.
  unsigned short* ob = o_part + ((size_t)half*BATCH*NH*SEQ + (size_t)(b*NH + h)*SEQ)*HD;
  float* lb = l_part + (size_t)half*BATCH*NH*SEQ + (size_t)(b*NH + h)*SEQ;
#pragma unroll
  for (int i = 0; i < 2; ++i) {
    float lsum = lrun[i];
    lsum += __shfl_xor(lsum, 16, 64);
    lsum += __shfl_xor(lsum, 32, 64);
    const float inv = (lsum > 0.f) ? 1.0f / lsum : 0.f;
    const int row = q0 + w*32 + i*16 + l15;
    if (l4 == 0) lb[row] = lsum;
#pragma unroll
    for (int td = 0; td < 8; ++td) {
      union { unsigned int u[2]; uint2 q; } pk;
      const float v0 = oacc[i][td][0]*inv, v1 = oacc[i][td][1]*inv;
      const float v2 = oacc[i][td][2]*inv, v3 = oacc[i][td][3]*inv;
      pk.u[0] = (unsigned int)f2bf(v0) | ((unsigned int)f2bf(v1) << 16);
      pk.u[1] = (unsigned int)f2bf(v2) | ((unsigned int)f2bf(v3) << 16);
      *(uint2*)(ob + (size_t)row*HD + td*16 + l4*4) = pk.q;
    }
  }
}

// ------------- combine: attn_o = (la*Oa + lb*Ob) / (la+lb) -------------
__global__ __launch_bounds__(256) void combine_kernel(
    const unsigned short* __restrict__ o_part,  // [2][B*NH*SEQ][HD] bf16
    const float* __restrict__ l_part,           // [2][B*NH*SEQ] fp32
    unsigned short* __restrict__ attn_o) {      // [B][SEQ][NH*HD] bf16
  const int tid = blockIdx.x * 256 + threadIdx.x;  // 1,048,576 threads
  const int d8 = tid & 15;                    // 16 chunks of 8 d
  const int row = tid >> 4;                   // (b*NH+h)*SEQ + s
  const int s = row & (SEQ-1);
  const int bh = row >> 11;
  const int h = bh & 15, b = bh >> 4;
  const float la = l_part[row];
  const float lbv = l_part[BATCH*NH*SEQ + row];
  const float inv = 1.f / (la + lbv);
  const float wa = la * inv, wb = lbv * inv;
  const unsigned short* pa = o_part + (size_t)row*HD + d8*8;
  const unsigned short* pb = pa + (size_t)BATCH*NH*SEQ*HD;
  uint4 ua = *(const uint4*)pa;
  uint4 ub = *(const uint4*)pb;
  const unsigned short* ea = (const unsigned short*)&ua;
  const unsigned short* eb = (const unsigned short*)&ub;
  union { unsigned short u[8]; uint4 q; } o;
#pragma unroll
  for (int k = 0; k < 8; ++k)
    o.u[k] = f2bf(bf2f(ea[k])*wa + bf2f(eb[k])*wb);
  *(uint4*)(attn_o + ((size_t)(b*SEQ + s)*(NH*HD)) + h*HD + d8*8) = o.q;
}

extern "C" void kernel_launch(void* const* d_in, const int* in_sizes, int n_in,
                              void* d_out, int out_size, void* d_ws, size_t ws_size,
                              hipStream_t stream) {
  const float* hs = (const float*)d_in[0];
  const int* pos  = (const int*)d_in[1];
  const float* Wq = (const float*)d_in[2];
  const float* Wk = (const float*)d_in[3];
  const float* Wv = (const float*)d_in[4];
  const float* Wo = (const float*)d_in[5];
  const float* qw = (const float*)d_in[6];
  const float* kw = (const float*)d_in[7];
  float* out = (float*)d_out;
  char* ws = (char*)d_ws;

  unsigned short* attn_o = (unsigned short*)(ws + 0);                    // 16 MB
  unsigned short* wot    = (unsigned short*)(ws + ((size_t)16 << 20));   // 4 MB
  unsigned short* q_l    = (unsigned short*)(ws + ((size_t)20 << 20));   // 16 MB
  unsigned short* k_l    = (unsigned short*)(ws + ((size_t)36 << 20));   // 8 MB
  unsigned short* vt8    = (unsigned short*)(ws + ((size_t)44 << 20));   // 8 MB
  unsigned short* o_part = (unsigned short*)(ws + ((size_t)52 << 20));   // 32 MB
  unsigned short* hsb    = (unsigned short*)(ws + ((size_t)52 << 20));   // 8 MB (alias)
  unsigned short* wqkvt  = (unsigned short*)(ws + ((size_t)60 << 20));   // 8 MB (alias)
  float*          l_part = (float*)(ws + ((size_t)84 << 20));            // 512 KB

  // 1. all converts in one launch (weights transpose-convert + hs convert)
  tcvt_all_kernel<<<dim3(7168), dim3(32, 8), 0, stream>>>(Wq, Wk, Wv, Wo, hs, wqkvt, wot, hsb);
  // 2. QKV projection + fused RMSNorm/RoPE/V-transpose epilogue (kappa-permuted vt8)
  gemm_qkv_fused_kernel<<<dim3(32, 32), dim3(256), 0, stream>>>(hsb, wqkvt, qw, kw, pos, q_l, k_l, vt8);
  // 3. flash attention: in-register P datapath on R1's memory config (2-D grid, dbuf K+V)
  attn_kernel<<<dim3(32, 32), dim3(256), 0, stream>>>(q_l, k_l, vt8, o_part, l_part);
  // 3b. combine partials -> attn_o
  combine_kernel<<<dim3(4096), dim3(256), 0, stream>>>(o_part, l_part, attn_o);
  // 4. output projection: 128x128 tiles, grid (N/128=8, M/128=32) = 256 blocks
  gemm_out_kernel<<<dim3(8, 32), dim3(256), 0, stream>>>(attn_o, wot, out, 4096, 1024, 2048);
}

// Round 11
// 256.393 us; speedup vs baseline: 1.3993x; 1.0071x over previous
//
#include <hip/hip_runtime.h>
#include <cstdint>
#include <cstddef>

#define HIDDEN 1024
#define NH 16
#define NKV 8
#define HD 128
#define SEQ 2048
#define BATCH 2
#define NTOK (BATCH*SEQ)        /* 4096 */

typedef __bf16 bf16x8 __attribute__((ext_vector_type(8)));
typedef float f32x4 __attribute__((ext_vector_type(4)));

__device__ __forceinline__ unsigned short f2bf(float f) {
  unsigned int u = __float_as_uint(f);
  u += 0x7FFFu + ((u >> 16) & 1u);          // round-to-nearest-even
  return (unsigned short)(u >> 16);
}
__device__ __forceinline__ float bf2f(unsigned short h) {
  return __uint_as_float(((unsigned int)h) << 16);
}

#if __has_builtin(__builtin_amdgcn_exp2f)
#define EXP2(x) __builtin_amdgcn_exp2f(x)
#else
#define EXP2(x) exp2f(x)
#endif

// async global->LDS, 16B per lane; LDS dest = uniform base + lane*16
__device__ __forceinline__ void glds16(const unsigned short* g, unsigned short* l) {
  __builtin_amdgcn_global_load_lds(
      (const __attribute__((address_space(1))) unsigned int*)g,
      (__attribute__((address_space(3))) unsigned int*)l, 16, 0, 0);
}

// s_waitcnt immediates (gfx9/CDNA: vmcnt[3:0]+[15:14], exp[6:4], lgkm[11:8])
#define WAIT_VM8()   __builtin_amdgcn_s_waitcnt(0x0F78)  /* vmcnt<=8 */
#define WAIT_VM4()   __builtin_amdgcn_s_waitcnt(0x0F74)  /* vmcnt<=4 */
#define WAIT_VM0()   __builtin_amdgcn_s_waitcnt(0x0F70)  /* vmcnt<=0 */
#define WAIT_LGKM0() __builtin_amdgcn_s_waitcnt(0xC07F)  /* lgkmcnt<=0 */
#define BARRIER()    __builtin_amdgcn_s_barrier()

// adjacent-lane (xor 1) exchange-add via quad_perm [1,0,3,2]
__device__ __forceinline__ float dpp_addx1(float x) {
  int v = __builtin_amdgcn_update_dpp(0, __float_as_int(x), 0xB1, 0xF, 0xF, true);
  return x + __int_as_float(v);
}

// ---- all-weights transpose-convert + hs convert, ONE launch ----
__global__ __launch_bounds__(256) void tcvt_all_kernel(
    const float* __restrict__ Wq, const float* __restrict__ Wk,
    const float* __restrict__ Wv, const float* __restrict__ Wo,
    const float* __restrict__ hs,
    unsigned short* __restrict__ wqkvt, unsigned short* __restrict__ wot,
    unsigned short* __restrict__ hsb) {
  const int i = blockIdx.x;
  const int tx = threadIdx.x, ty = threadIdx.y;
  if (i >= 6144) {                           // hs convert: 1024 blocks x 4096 elems
    const int t = ty*32 + tx;
    const size_t base = (size_t)(i - 6144) * 1024;   // in float4 units
#pragma unroll
    for (int j = 0; j < 4; ++j) {
      const size_t idx = base + j*256 + t;
      float4 v = ((const float4*)hs)[idx];
      ushort4 o;
      o.x = f2bf(v.x); o.y = f2bf(v.y); o.z = f2bf(v.z); o.w = f2bf(v.w);
      ((ushort4*)hsb)[idx] = o;
    }
    return;
  }
  __shared__ float tl[32][33];
  const float* src; unsigned short* dst; int R, C, r0, c0;
  if (i < 2048)      { int l = i;        src = Wq; dst = wqkvt;                      R = 1024; C = 2048; r0 = (l & 31)*32; c0 = (l >> 5)*32; }
  else if (i < 3072) { int l = i - 2048; src = Wk; dst = wqkvt + (size_t)2048*1024;  R = 1024; C = 1024; r0 = (l & 31)*32; c0 = (l >> 5)*32; }
  else if (i < 4096) { int l = i - 3072; src = Wv; dst = wqkvt + (size_t)3072*1024;  R = 1024; C = 1024; r0 = (l & 31)*32; c0 = (l >> 5)*32; }
  else               { int l = i - 4096; src = Wo; dst = wot;                        R = 2048; C = 1024; r0 = (l & 63)*32; c0 = (l >> 6)*32; }
#pragma unroll
  for (int k = 0; k < 4; ++k)
    tl[ty + 8*k][tx] = src[(size_t)(r0 + ty + 8*k)*C + c0 + tx];
  __syncthreads();
#pragma unroll
  for (int k = 0; k < 4; ++k)
    dst[(size_t)(c0 + ty + 8*k)*R + r0 + tx] = f2bf(tl[tx][ty + 8*k]);
}

// -------- QKV GEMM (128x128, BK=64, async dbuf) + fused norm/rope/vtrans --------
// R12: vt8 written in kappa-permuted kv order (within each 64-kv block:
// kv = s2*32 + e2*16 + s1*8 + s0*4 + e1*2 + e0 for slot (slice s, elem e))
// so the attn PV B-fragment (P^T) needs NO cross-lane repack.
__global__ __launch_bounds__(256) void gemm_qkv_fused_kernel(
    const unsigned short* __restrict__ A,      // hs bf16 [4096][1024]
    const unsigned short* __restrict__ Bt,     // wqkvt bf16 [4096][1024]
    const float* __restrict__ qw, const float* __restrict__ kw,
    const int* __restrict__ pos_ids,
    unsigned short* __restrict__ q_l,
    unsigned short* __restrict__ k_l,
    unsigned short* __restrict__ vt8) {
  constexpr int BM = 128, BK = 64, K = 1024, NIT = K/BK;
  __shared__ __align__(16) char smem[70144];   // 68.5 KB -> 2 blocks/CU
  unsigned short* As0 = (unsigned short*)smem;           // 2 x 16 KB
  unsigned short* Bs0 = (unsigned short*)(smem + 32768); // 2 x 16 KB
  float* ftile = (float*)smem;                           // 128 x 136 fp32 (68 KB)
  float* rinv  = (float*)(smem + 69632);                 // 128 fp32

  const int t = threadIdx.x, lane = t & 63, w = t >> 6;
  const int l15 = lane & 15, l4 = lane >> 4;
  const int wr = (w >> 1)*64, wc = (w & 1)*64;
  const int m0 = blockIdx.x * BM, n0 = blockIdx.y * 128;
  const unsigned short* Ab = A + (size_t)m0*K;
  const unsigned short* Bb = Bt + (size_t)n0*K;

  const f32x4 vzero = {0.f, 0.f, 0.f, 0.f};
  f32x4 acc[4][4];
#pragma unroll
  for (int i = 0; i < 4; ++i)
#pragma unroll
    for (int j = 0; j < 4; ++j) acc[i][j] = vzero;

#pragma unroll
  for (int i = 0; i < 4; ++i) {
    const int c = (w*4 + i)*64 + lane;
    glds16(Ab + (size_t)(c >> 3)*K + (c & 7)*8, As0 + (size_t)(w*4 + i)*512);
  }
#pragma unroll
  for (int i = 0; i < 4; ++i) {
    const int c = (w*4 + i)*64 + lane;
    glds16(Bb + (size_t)(c >> 3)*K + (c & 7)*8, Bs0 + (size_t)(w*4 + i)*512);
  }

  for (int kb = 0; kb < NIT; ++kb) {
    const int cur = kb & 1;
    WAIT_LGKM0(); BARRIER();
    if (kb + 1 < NIT) {
      const int kn = (kb + 1) * BK;
      const int nb = (cur^1)*8192;
#pragma unroll
      for (int i = 0; i < 4; ++i) {
        const int c = (w*4 + i)*64 + lane;
        glds16(Ab + (size_t)(c >> 3)*K + kn + (c & 7)*8, As0 + nb + (size_t)(w*4 + i)*512);
      }
#pragma unroll
      for (int i = 0; i < 4; ++i) {
        const int c = (w*4 + i)*64 + lane;
        glds16(Bb + (size_t)(c >> 3)*K + kn + (c & 7)*8, Bs0 + nb + (size_t)(w*4 + i)*512);
      }
      WAIT_VM8();
    } else {
      WAIT_VM0();
    }
    BARRIER();

    const unsigned short* Ac = As0 + cur*8192;
    const unsigned short* Bc = Bs0 + cur*8192;
#pragma unroll
    for (int kk = 0; kk < 2; ++kk) {
      const int kc = kk*4 + l4;
      bf16x8 af[4], bfr[4];
#pragma unroll
      for (int i = 0; i < 4; ++i) {
        int m = wr + i*16 + l15;
        af[i] = *(const bf16x8*)(Ac + ((size_t)m*8 + kc)*8);
      }
#pragma unroll
      for (int j = 0; j < 4; ++j) {
        int n = wc + j*16 + l15;
        bfr[j] = *(const bf16x8*)(Bc + ((size_t)n*8 + kc)*8);
      }
#pragma unroll
      for (int i = 0; i < 4; ++i)
#pragma unroll
        for (int j = 0; j < 4; ++j)
          acc[i][j] = __builtin_amdgcn_mfma_f32_16x16x32_bf16(af[i], bfr[j], acc[i][j], 0, 0, 0);
    }
  }

  // ---- epilogue: spill C-tile to LDS fp32 [128][136] ----
  WAIT_LGKM0(); BARRIER();
#pragma unroll
  for (int i = 0; i < 4; ++i)
#pragma unroll
    for (int j = 0; j < 4; ++j)
#pragma unroll
      for (int r = 0; r < 4; ++r) {
        const int row = wr + i*16 + l4*4 + r;
        const int col = wc + j*16 + l15;
        ftile[row*136 + col] = acc[i][j][r];
      }
  WAIT_LGKM0(); BARRIER();

  const int ny = n0 >> 7;                    // 0..15 q-head, 16..23 k-head, 24..31 v-head
  const int S0 = m0 & (SEQ-1);
  const int bb = m0 >> 11;

  if (ny < 24) {
    const bool isQ = ny < 16;
    {
      const int row = t >> 1, h2 = t & 1;
      const float* fr = ftile + row*136 + h2*64;
      float ssq = 0.f;
#pragma unroll
      for (int c = 0; c < 16; ++c) {
        float4 v = *(const float4*)(fr + 4*c);
        ssq += v.x*v.x + v.y*v.y + v.z*v.z + v.w*v.w;
      }
      ssq = dpp_addx1(ssq);
      if (h2 == 0) rinv[row] = rsqrtf(ssq*(1.0f/128.0f) + 1e-6f);
    }
    WAIT_LGKM0(); BARRIER();
    const float* wgt = isQ ? qw : kw;
    const int d = t & 127, rh = t >> 7;
    const float wd = wgt[d];
    const float w2 = wgt[d ^ 64];
    const float sgn = (d < 64) ? -1.f : 1.f;
    const float sOut = isQ ? 0.12751744f : 1.f;     // (1/sqrt(128))*log2(e) folded into q
    const float invf = exp2f(-(float)(d & 63) * 0.31143075889569023f);
    const int pos0 = pos_ids[S0 + rh*64];
    float cs, sn, dc, dsn;
    __sincosf((float)pos0 * invf, &sn, &cs);
    __sincosf(invf, &dsn, &dc);
    const int head = isQ ? ny : (ny - 16);
    unsigned short* dstb = isQ ? (q_l + ((size_t)(bb*NH + head)*SEQ + S0)*HD)
                               : (k_l + ((size_t)(bb*NKV + head)*SEQ + S0)*HD);
#pragma unroll 4
    for (int k = 0; k < 64; ++k) {
      const int row = rh*64 + k;
      const float r  = rinv[row];
      const float x1 = ftile[row*136 + d];
      const float x2 = ftile[row*136 + (d ^ 64)];
      const float y1 = x1*r*wd, y2 = x2*r*w2;
      const float o  = (y1*cs + sgn*(y2*sn)) * sOut;
      dstb[(size_t)row*HD + d] = f2bf(o);
      const float c2 = cs*dc - sn*dsn;       // rotate: pos -> pos+1
      sn = sn*dc + cs*dsn; cs = c2;
    }
  } else {
    // V-epilogue: kappa-permuted store. Slot (slice sl, elem s8) holds
    // C-row = blk*64 + s2*32 + e2*16 + s1*8 + s0*4 + e1*2 + e0.
    const int vh = ny - 24;
    unsigned short* vb = vt8 + (size_t)(bb*NKV + vh)*HD*SEQ;
    const int d = t & 127, sbh = t >> 7;
#pragma unroll
    for (int sb = 0; sb < 8; ++sb) {
      const int sl = sbh*8 + sb;
      const int blk = sl >> 3, s = sl & 7;
      const int base_r = blk*64 + ((s>>2)<<5) + (((s>>1)&1)<<3) + ((s&1)<<2);
      union { unsigned short u[8]; uint4 q; } pk;
#pragma unroll
      for (int s8 = 0; s8 < 8; ++s8) {
        const int row = base_r + ((s8>>2)<<4) + (((s8>>1)&1)<<1) + (s8&1);
        pk.u[s8] = f2bf(ftile[row*136 + d]);
      }
      *(uint4*)(vb + ((size_t)((S0 >> 3) + sl)*128 + d)*8) = pk.q;
    }
  }
}

// ------------- bf16 GEMM (out-proj): 128x128 tile, fp32 out -------------
__global__ __launch_bounds__(256) void gemm_out_kernel(
    const unsigned short* __restrict__ A,
    const unsigned short* __restrict__ Bt,
    float* __restrict__ Cout, int M, int N, int K) {
  constexpr int BK = 64;
  __shared__ unsigned short As[2][128*BK];   // 2 x 16 KB
  __shared__ unsigned short Bs[2][128*BK];   // 2 x 16 KB  -> 64 KB, 2 blocks/CU
  const int t = threadIdx.x, lane = t & 63, w = t >> 6;
  const int l15 = lane & 15, l4 = lane >> 4;
  const int wr = (w >> 1)*64, wc = (w & 1)*64;
  const int m0 = blockIdx.y * 128, n0 = blockIdx.x * 128;
  const unsigned short* Ab = A + (size_t)m0*K;
  const unsigned short* Bb = Bt + (size_t)n0*K;

  const f32x4 vzero = {0.f, 0.f, 0.f, 0.f};
  f32x4 acc[4][4];
#pragma unroll
  for (int i = 0; i < 4; ++i)
#pragma unroll
    for (int j = 0; j < 4; ++j) acc[i][j] = vzero;

  const int NIT = K / BK;
#pragma unroll
  for (int i = 0; i < 4; ++i) {
    const int c = (w*4 + i)*64 + lane;
    glds16(Ab + (size_t)(c >> 3)*K + (c & 7)*8, &As[0][(size_t)(w*4 + i)*512]);
  }
#pragma unroll
  for (int i = 0; i < 4; ++i) {
    const int c = (w*4 + i)*64 + lane;
    glds16(Bb + (size_t)(c >> 3)*K + (c & 7)*8, &Bs[0][(size_t)(w*4 + i)*512]);
  }

  for (int kb = 0; kb < NIT; ++kb) {
    const int cur = kb & 1;
    WAIT_LGKM0(); BARRIER();
    if (kb + 1 < NIT) {
      const int kn = (kb + 1) * BK;
#pragma unroll
      for (int i = 0; i < 4; ++i) {
        const int c = (w*4 + i)*64 + lane;
        glds16(Ab + (size_t)(c >> 3)*K + kn + (c & 7)*8, &As[cur^1][(size_t)(w*4 + i)*512]);
      }
#pragma unroll
      for (int i = 0; i < 4; ++i) {
        const int c = (w*4 + i)*64 + lane;
        glds16(Bb + (size_t)(c >> 3)*K + kn + (c & 7)*8, &Bs[cur^1][(size_t)(w*4 + i)*512]);
      }
      WAIT_VM8();
    } else {
      WAIT_VM0();
    }
    BARRIER();

#pragma unroll
    for (int kk = 0; kk < 2; ++kk) {
      const int kc = kk*4 + l4;
      bf16x8 af[4], bfr[4];
#pragma unroll
      for (int i = 0; i < 4; ++i) {
        int m = wr + i*16 + l15;
        af[i] = *(const bf16x8*)(&As[cur][((size_t)m*8 + kc)*8]);
      }
#pragma unroll
      for (int j = 0; j < 4; ++j) {
        int n = wc + j*16 + l15;
        bfr[j] = *(const bf16x8*)(&Bs[cur][((size_t)n*8 + kc)*8]);
      }
#pragma unroll
      for (int i = 0; i < 4; ++i)
#pragma unroll
        for (int j = 0; j < 4; ++j)
          acc[i][j] = __builtin_amdgcn_mfma_f32_16x16x32_bf16(af[i], bfr[j], acc[i][j], 0, 0, 0);
    }
  }
#pragma unroll
  for (int i = 0; i < 4; ++i)
#pragma unroll
    for (int j = 0; j < 4; ++j)
#pragma unroll
      for (int r = 0; r < 4; ++r) {
        int row = m0 + wr + i*16 + l4*4 + r;
        int col = n0 + wc + j*16 + l15;
        Cout[(size_t)row*N + col] = acc[i][j][r];
      }
}

// ------------- Flash attention, causal, GQA head-pair fused -------------
// R15: GQA pair fusion. R14 confirmed compulsory FETCH (32 MB) but dur only
// -2%: attn is VALU/occupancy-bound (MfmaUtil 23 + VALU 37, Occ 18% = 2
// waves/SIMD; 32 exp2/lane/iter on the quarter-rate trans pipe can't overlap
// MFMA with so few waves). Fix: heads 2k,2k+1 share K/V -> fuse the pair into
// one 512-thread 8-wave block (waves 0-3 head 2k, 4-7 head 2k+1; BQ=64/head),
// sharing one K/V staging. Preserves R14's proven memory config exactly:
// 2 blocks/CU (LDS 64KB x2), hb-fast grid, dbuf + counted vmcnt (4 loads/wave
// -> WAIT_VM4), same arithmetic intensity per staged byte -> FETCH stays
// compulsory. Occupancy doubles to 4 waves/SIMD.
// Grid: (16 pairs, 64 y) = 32 q-strips x 2 KV-halves, longest-first LPT.
__global__ __launch_bounds__(512, 4) void attn_kernel(
    const unsigned short* __restrict__ q_l,
    const unsigned short* __restrict__ k_l,
    const unsigned short* __restrict__ vt8,
    unsigned short* __restrict__ o_part,   // [2][B][NH][SEQ][HD] bf16
    float* __restrict__ l_part) {          // [2][B][NH][SEQ] fp32
  __shared__ __align__(16) char smem[65536];
  unsigned short* Ks0  = (unsigned short*)smem;            // 2 x 16 KB dbuf
  unsigned short* Vts0 = (unsigned short*)(smem + 32768);  // 2 x 16 KB dbuf

  const int t = threadIdx.x;
  const int lane = t & 63;
  const int w = t >> 6;                      // 0..7
  const int l15 = lane & 15, l4 = lane >> 4;
  const int p = blockIdx.x;                  // kvh + 8*b (fast dim: K/V L2 share)
  const int kvh = p & 7, b = p >> 3;
  const int h = kvh*2 + (w >> 2);            // wave's head
  const int wq = w & 3;                      // wave's q-subtile within strip
  const int y = blockIdx.y;                  // 0..63
  const int qt = 31 - (y >> 1);              // longest first (64-row strips)
  const int half = y & 1;
  const int q0 = qt * 64;
  const int T  = qt + 1;                     // KV tiles for this strip
  const int h0 = (T + 1) >> 1;
  const int kt0 = half ? h0 : 0;
  const int kt1 = half ? T : h0;

  const unsigned short* Kg = k_l + ((size_t)(b*NKV + kvh)*SEQ)*HD;
  const unsigned short* Vg = vt8 + (size_t)(b*NKV + kvh)*HD*SEQ;
  const unsigned short* Qbase = q_l + ((size_t)(b*NH + h)*SEQ)*HD;

  const f32x4 vzero = {0.f,0.f,0.f,0.f};

  // Q fragments in registers (already scaled by 1/sqrt(d)*log2e): 16 rows/wave
  bf16x8 qf[4];
  {
    const int row = q0 + wq*16 + l15;
    const unsigned short* Qp = Qbase + (size_t)row*HD;
#pragma unroll
    for (int kk = 0; kk < 4; ++kk)
      qf[kk] = *(const bf16x8*)(Qp + kk*32 + l4*8);
  }

  f32x4 oacc[8];                             // O^T: [d-tile], q = l15
#pragma unroll
  for (int jd = 0; jd < 8; ++jd) oacc[jd] = vzero;
  float lrun = 0.f;                          // per-lane partial row sum

  if (kt0 < kt1) {
    // prologue: issue K(kt0)+V(kt0) into buf 0 (4 loads/wave, 32 total)
    {
      const int k00 = kt0 * 64;
#pragma unroll
      for (int i = 0; i < 2; ++i) {          // K tile: kc = w*2+i in 0..15
        const int kc = w*2 + i;
        const int m = lane ^ (kc & 7);
        glds16(Kg + (size_t)(k00 + m)*HD + kc*8, Ks0 + (size_t)kc*64*8);
      }
#pragma unroll
      for (int i = 0; i < 2; ++i) {          // V tile (kappa-permuted vt8)
        const int id = w*2 + i;
        const int skc = id >> 1, hh = id & 1;
        const int d = (hh*64 + lane) ^ skc;
        glds16(Vg + ((size_t)((k00 >> 3) + skc)*128 + d)*8, Vts0 + (size_t)(skc*128 + hh*64)*8);
      }
    }

#pragma unroll 1
    for (int kt = kt0; kt < kt1; ++kt) {
      const int cur = (kt - kt0) & 1;
      const int k0 = kt * 64;
      WAIT_LGKM0(); BARRIER();               // all waves done reading buf cur^1
      if (kt + 1 < kt1) {                    // prefetch kt+1 into buf cur^1
        const int kn = k0 + 64;
        unsigned short* Ksn  = Ks0  + (cur^1)*8192;
        unsigned short* Vtsn = Vts0 + (cur^1)*8192;
#pragma unroll
        for (int i = 0; i < 2; ++i) {
          const int kc = w*2 + i;
          const int m = lane ^ (kc & 7);
          glds16(Kg + (size_t)(kn + m)*HD + kc*8, Ksn + (size_t)kc*64*8);
        }
#pragma unroll
        for (int i = 0; i < 2; ++i) {
          const int id = w*2 + i;
          const int skc = id >> 1, hh = id & 1;
          const int d = (hh*64 + lane) ^ skc;
          glds16(Vg + ((size_t)((kn >> 3) + skc)*128 + d)*8, Vtsn + (size_t)(skc*128 + hh*64)*8);
        }
        WAIT_VM4();                           // drain only cur's 4 loads
      } else {
        WAIT_VM0();
      }
      BARRIER();                              // buf cur fully staged

      const unsigned short* KsC  = Ks0  + cur*8192;
      const unsigned short* VtsC = Vts0 + cur*8192;

      // S^T = K Q^T (lane: q = l15, kv = j*16 + l4*4 + r)
      f32x4 sacc[4];
#pragma unroll
      for (int j = 0; j < 4; ++j) sacc[j] = vzero;
      __builtin_amdgcn_s_setprio(1);
#pragma unroll
      for (int kk = 0; kk < 4; ++kk) {
        const int kc = kk*4 + l4;
        bf16x8 kb[4];
#pragma unroll
        for (int j = 0; j < 4; ++j) {
          int n = j*16 + l15;
          kb[j] = *(const bf16x8*)(KsC + ((size_t)kc*64 + (n ^ (kc & 7)))*8);
        }
#pragma unroll
        for (int j = 0; j < 4; ++j)
          sacc[j] = __builtin_amdgcn_mfma_f32_16x16x32_bf16(kb[j], qf[kk], sacc[j], 0,0,0);
      }
      __builtin_amdgcn_s_setprio(0);

      // P = exp2(S) (no max); causal mask only on the diag tile (kt == qt)
      const bool diag = (kt == qt);
#pragma unroll
      for (int j = 0; j < 4; ++j)
#pragma unroll
        for (int r = 0; r < 4; ++r) {
          float sv = sacc[j][r];
          if (diag) {
            const int kvg = k0 + j*16 + l4*4 + r;
            const int qg  = q0 + wq*16 + l15;
            sv = (kvg > qg) ? -INFINITY : sv;
          }
          float pv = EXP2(sv);
          sacc[j][r] = pv;
          lrun += pv;
        }

      // O^T += V^T P^T  (A = V^T frag from LDS, B = own packed P)
#pragma unroll
      for (int kk = 0; kk < 2; ++kk) {
        union { unsigned int u[4]; bf16x8 v; } pb;
        {
          const f32x4 t0 = sacc[kk*2], t1 = sacc[kk*2+1];
          pb.u[0] = (__float_as_uint(t0[0]) >> 16) | (__float_as_uint(t0[1]) & 0xFFFF0000u);
          pb.u[1] = (__float_as_uint(t0[2]) >> 16) | (__float_as_uint(t0[3]) & 0xFFFF0000u);
          pb.u[2] = (__float_as_uint(t1[0]) >> 16) | (__float_as_uint(t1[1]) & 0xFFFF0000u);
          pb.u[3] = (__float_as_uint(t1[2]) >> 16) | (__float_as_uint(t1[3]) & 0xFFFF0000u);
        }
        const int s = kk*4 + l4;
        __builtin_amdgcn_s_setprio(1);
#pragma unroll
        for (int td = 0; td < 8; ++td) {
          const int dd = td*16 + l15;
          bf16x8 va = *(const bf16x8*)(VtsC + ((size_t)s*128 + (dd ^ s))*8);
          oacc[td] = __builtin_amdgcn_mfma_f32_16x16x32_bf16(va, pb.v, oacc[td], 0,0,0);
        }
        __builtin_amdgcn_s_setprio(0);
      }
    }
  }

  // epilogue: reduce lrun across the 4 l4-groups, normalize, store O^T.
  // Empty half (qt=0, half=1): lrun=0 -> inv=0 -> true zeros stored.
  unsigned short* ob = o_part + ((size_t)half*BATCH*NH*SEQ + (size_t)(b*NH + h)*SEQ)*HD;
  float* lb = l_part + (size_t)half*BATCH*NH*SEQ + (size_t)(b*NH + h)*SEQ;
  {
    float lsum = lrun;
    lsum += __shfl_xor(lsum, 16, 64);
    lsum += __shfl_xor(lsum, 32, 64);
    const float inv = (lsum > 0.f) ? 1.0f / lsum : 0.f;
    const int row = q0 + wq*16 + l15;
    if (l4 == 0) lb[row] = lsum;
#pragma unroll
    for (int td = 0; td < 8; ++td) {
      union { unsigned int u[2]; uint2 q; } pk;
      const float v0 = oacc[td][0]*inv, v1 = oacc[td][1]*inv;
      const float v2 = oacc[td][2]*inv, v3 = oacc[td][3]*inv;
      pk.u[0] = (unsigned int)f2bf(v0) | ((unsigned int)f2bf(v1) << 16);
      pk.u[1] = (unsigned int)f2bf(v2) | ((unsigned int)f2bf(v3) << 16);
      *(uint2*)(ob + (size_t)row*HD + td*16 + l4*4) = pk.q;
    }
  }
}

// ------------- combine: attn_o = (la*Oa + lb*Ob) / (la+lb) -------------
__global__ __launch_bounds__(256) void combine_kernel(
    const unsigned short* __restrict__ o_part,  // [2][B*NH*SEQ][HD] bf16
    const float* __restrict__ l_part,           // [2][B*NH*SEQ] fp32
    unsigned short* __restrict__ attn_o) {      // [B][SEQ][NH*HD] bf16
  const int tid = blockIdx.x * 256 + threadIdx.x;  // 1,048,576 threads
  const int d8 = tid & 15;                    // 16 chunks of 8 d
  const int row = tid >> 4;                   // (b*NH+h)*SEQ + s
  const int s = row & (SEQ-1);
  const int bh = row >> 11;
  const int h = bh & 15, b = bh >> 4;
  const float la = l_part[row];
  const float lbv = l_part[BATCH*NH*SEQ + row];
  const float inv = 1.f / (la + lbv);
  const float wa = la * inv, wb = lbv * inv;
  const unsigned short* pa = o_part + (size_t)row*HD + d8*8;
  const unsigned short* pb = pa + (size_t)BATCH*NH*SEQ*HD;
  uint4 ua = *(const uint4*)pa;
  uint4 ub = *(const uint4*)pb;
  const unsigned short* ea = (const unsigned short*)&ua;
  const unsigned short* eb = (const unsigned short*)&ub;
  union { unsigned short u[8]; uint4 q; } o;
#pragma unroll
  for (int k = 0; k < 8; ++k)
    o.u[k] = f2bf(bf2f(ea[k])*wa + bf2f(eb[k])*wb);
  *(uint4*)(attn_o + ((size_t)(b*SEQ + s)*(NH*HD)) + h*HD + d8*8) = o.q;
}

extern "C" void kernel_launch(void* const* d_in, const int* in_sizes, int n_in,
                              void* d_out, int out_size, void* d_ws, size_t ws_size,
                              hipStream_t stream) {
  const float* hs = (const float*)d_in[0];
  const int* pos  = (const int*)d_in[1];
  const float* Wq = (const float*)d_in[2];
  const float* Wk = (const float*)d_in[3];
  const float* Wv = (const float*)d_in[4];
  const float* Wo = (const float*)d_in[5];
  const float* qw = (const float*)d_in[6];
  const float* kw = (const float*)d_in[7];
  float* out = (float*)d_out;
  char* ws = (char*)d_ws;

  unsigned short* attn_o = (unsigned short*)(ws + 0);                    // 16 MB
  unsigned short* wot    = (unsigned short*)(ws + ((size_t)16 << 20));   // 4 MB
  unsigned short* q_l    = (unsigned short*)(ws + ((size_t)20 << 20));   // 16 MB
  unsigned short* k_l    = (unsigned short*)(ws + ((size_t)36 << 20));   // 8 MB
  unsigned short* vt8    = (unsigned short*)(ws + ((size_t)44 << 20));   // 8 MB
  unsigned short* o_part = (unsigned short*)(ws + ((size_t)52 << 20));   // 32 MB
  unsigned short* hsb    = (unsigned short*)(ws + ((size_t)52 << 20));   // 8 MB (alias)
  unsigned short* wqkvt  = (unsigned short*)(ws + ((size_t)60 << 20));   // 8 MB (alias)
  float*          l_part = (float*)(ws + ((size_t)84 << 20));            // 512 KB

  // 1. all converts in one launch (weights transpose-convert + hs convert)
  tcvt_all_kernel<<<dim3(7168), dim3(32, 8), 0, stream>>>(Wq, Wk, Wv, Wo, hs, wqkvt, wot, hsb);
  // 2. QKV projection + fused RMSNorm/RoPE/V-transpose epilogue (kappa-permuted vt8)
  gemm_qkv_fused_kernel<<<dim3(32, 32), dim3(256), 0, stream>>>(hsb, wqkvt, qw, kw, pos, q_l, k_l, vt8);
  // 3. flash attention: GQA head-pair fused, 8 waves/block, 4 waves/SIMD
  attn_kernel<<<dim3(16, 64), dim3(512), 0, stream>>>(q_l, k_l, vt8, o_part, l_part);
  // 3b. combine partials -> attn_o
  combine_kernel<<<dim3(4096), dim3(256), 0, stream>>>(o_part, l_part, attn_o);
  // 4. output projection: 128x128 tiles, grid (N/128=8, M/128=32) = 256 blocks
  gemm_out_kernel<<<dim3(8, 32), dim3(256), 0, stream>>>(attn_o, wot, out, 4096, 1024, 2048);
}

// Round 12
// 255.523 us; speedup vs baseline: 1.4041x; 1.0034x over previous
//
#include <hip/hip_runtime.h>
#include <cstdint>
#include <cstddef>

#define HIDDEN 1024
#define NH 16
#define NKV 8
#define HD 128
#define SEQ 2048
#define BATCH 2
#define NTOK (BATCH*SEQ)        /* 4096 */

typedef __bf16 bf16x8 __attribute__((ext_vector_type(8)));
typedef float f32x4 __attribute__((ext_vector_type(4)));

__device__ __forceinline__ unsigned short f2bf(float f) {
  unsigned int u = __float_as_uint(f);
  u += 0x7FFFu + ((u >> 16) & 1u);          // round-to-nearest-even
  return (unsigned short)(u >> 16);
}
__device__ __forceinline__ float bf2f(unsigned short h) {
  return __uint_as_float(((unsigned int)h) << 16);
}

#if __has_builtin(__builtin_amdgcn_exp2f)
#define EXP2(x) __builtin_amdgcn_exp2f(x)
#else
#define EXP2(x) exp2f(x)
#endif

// async global->LDS, 16B per lane; LDS dest = uniform base + lane*16
__device__ __forceinline__ void glds16(const unsigned short* g, unsigned short* l) {
  __builtin_amdgcn_global_load_lds(
      (const __attribute__((address_space(1))) unsigned int*)g,
      (__attribute__((address_space(3))) unsigned int*)l, 16, 0, 0);
}

// s_waitcnt immediates (gfx9/CDNA: vmcnt[3:0]+[15:14], exp[6:4], lgkm[11:8])
#define WAIT_VM8()   __builtin_amdgcn_s_waitcnt(0x0F78)  /* vmcnt<=8 */
#define WAIT_VM4()   __builtin_amdgcn_s_waitcnt(0x0F74)  /* vmcnt<=4 */
#define WAIT_VM0()   __builtin_amdgcn_s_waitcnt(0x0F70)  /* vmcnt<=0 */
#define WAIT_LGKM0() __builtin_amdgcn_s_waitcnt(0xC07F)  /* lgkmcnt<=0 */
#define BARRIER()    __builtin_amdgcn_s_barrier()

// adjacent-lane (xor 1) exchange-add via quad_perm [1,0,3,2]
__device__ __forceinline__ float dpp_addx1(float x) {
  int v = __builtin_amdgcn_update_dpp(0, __float_as_int(x), 0xB1, 0xF, 0xF, true);
  return x + __int_as_float(v);
}

// ---- all-weights transpose-convert + hs convert, ONE launch ----
__global__ __launch_bounds__(256) void tcvt_all_kernel(
    const float* __restrict__ Wq, const float* __restrict__ Wk,
    const float* __restrict__ Wv, const float* __restrict__ Wo,
    const float* __restrict__ hs,
    unsigned short* __restrict__ wqkvt, unsigned short* __restrict__ wot,
    unsigned short* __restrict__ hsb) {
  const int i = blockIdx.x;
  const int tx = threadIdx.x, ty = threadIdx.y;
  if (i >= 6144) {                           // hs convert: 1024 blocks x 4096 elems
    const int t = ty*32 + tx;
    const size_t base = (size_t)(i - 6144) * 1024;   // in float4 units
#pragma unroll
    for (int j = 0; j < 4; ++j) {
      const size_t idx = base + j*256 + t;
      float4 v = ((const float4*)hs)[idx];
      ushort4 o;
      o.x = f2bf(v.x); o.y = f2bf(v.y); o.z = f2bf(v.z); o.w = f2bf(v.w);
      ((ushort4*)hsb)[idx] = o;
    }
    return;
  }
  __shared__ float tl[32][33];
  const float* src; unsigned short* dst; int R, C, r0, c0;
  if (i < 2048)      { int l = i;        src = Wq; dst = wqkvt;                      R = 1024; C = 2048; r0 = (l & 31)*32; c0 = (l >> 5)*32; }
  else if (i < 3072) { int l = i - 2048; src = Wk; dst = wqkvt + (size_t)2048*1024;  R = 1024; C = 1024; r0 = (l & 31)*32; c0 = (l >> 5)*32; }
  else if (i < 4096) { int l = i - 3072; src = Wv; dst = wqkvt + (size_t)3072*1024;  R = 1024; C = 1024; r0 = (l & 31)*32; c0 = (l >> 5)*32; }
  else               { int l = i - 4096; src = Wo; dst = wot;                        R = 2048; C = 1024; r0 = (l & 63)*32; c0 = (l >> 6)*32; }
#pragma unroll
  for (int k = 0; k < 4; ++k)
    tl[ty + 8*k][tx] = src[(size_t)(r0 + ty + 8*k)*C + c0 + tx];
  __syncthreads();
#pragma unroll
  for (int k = 0; k < 4; ++k)
    dst[(size_t)(c0 + ty + 8*k)*R + r0 + tx] = f2bf(tl[tx][ty + 8*k]);
}

// -------- QKV GEMM (128x128, BK=64, async dbuf) + fused norm/rope/vtrans --------
// R12: vt8 written in kappa-permuted kv order so the attn PV B-fragment (P^T)
// needs NO cross-lane repack.
// R16: ftile stride 136 -> 132 words (136 = 8 mod 32 banks -> 4-way conflict
// on acc-spill, 16-way on rmsnorm float4 reads; 1.33e7 SQ_LDS_BANK_CONFLICT.
// 132 = 4 mod 32 -> spill 2-way (free), rmsnorm 8-way, rope/v-reads 2-way).
__global__ __launch_bounds__(256) void gemm_qkv_fused_kernel(
    const unsigned short* __restrict__ A,      // hs bf16 [4096][1024]
    const unsigned short* __restrict__ Bt,     // wqkvt bf16 [4096][1024]
    const float* __restrict__ qw, const float* __restrict__ kw,
    const int* __restrict__ pos_ids,
    unsigned short* __restrict__ q_l,
    unsigned short* __restrict__ k_l,
    unsigned short* __restrict__ vt8) {
  constexpr int BM = 128, BK = 64, K = 1024, NIT = K/BK;
  constexpr int FS = 132;                      // ftile row stride (fp32 words)
  __shared__ __align__(16) char smem[70144];   // 68.5 KB -> 2 blocks/CU
  unsigned short* As0 = (unsigned short*)smem;           // 2 x 16 KB
  unsigned short* Bs0 = (unsigned short*)(smem + 32768); // 2 x 16 KB
  float* ftile = (float*)smem;                           // 128 x 132 fp32 (67.6 KB)
  float* rinv  = (float*)(smem + 69632);                 // 128 fp32

  const int t = threadIdx.x, lane = t & 63, w = t >> 6;
  const int l15 = lane & 15, l4 = lane >> 4;
  const int wr = (w >> 1)*64, wc = (w & 1)*64;
  const int m0 = blockIdx.x * BM, n0 = blockIdx.y * 128;
  const unsigned short* Ab = A + (size_t)m0*K;
  const unsigned short* Bb = Bt + (size_t)n0*K;

  const f32x4 vzero = {0.f, 0.f, 0.f, 0.f};
  f32x4 acc[4][4];
#pragma unroll
  for (int i = 0; i < 4; ++i)
#pragma unroll
    for (int j = 0; j < 4; ++j) acc[i][j] = vzero;

#pragma unroll
  for (int i = 0; i < 4; ++i) {
    const int c = (w*4 + i)*64 + lane;
    glds16(Ab + (size_t)(c >> 3)*K + (c & 7)*8, As0 + (size_t)(w*4 + i)*512);
  }
#pragma unroll
  for (int i = 0; i < 4; ++i) {
    const int c = (w*4 + i)*64 + lane;
    glds16(Bb + (size_t)(c >> 3)*K + (c & 7)*8, Bs0 + (size_t)(w*4 + i)*512);
  }

  for (int kb = 0; kb < NIT; ++kb) {
    const int cur = kb & 1;
    WAIT_LGKM0(); BARRIER();
    if (kb + 1 < NIT) {
      const int kn = (kb + 1) * BK;
      const int nb = (cur^1)*8192;
#pragma unroll
      for (int i = 0; i < 4; ++i) {
        const int c = (w*4 + i)*64 + lane;
        glds16(Ab + (size_t)(c >> 3)*K + kn + (c & 7)*8, As0 + nb + (size_t)(w*4 + i)*512);
      }
#pragma unroll
      for (int i = 0; i < 4; ++i) {
        const int c = (w*4 + i)*64 + lane;
        glds16(Bb + (size_t)(c >> 3)*K + kn + (c & 7)*8, Bs0 + nb + (size_t)(w*4 + i)*512);
      }
      WAIT_VM8();
    } else {
      WAIT_VM0();
    }
    BARRIER();

    const unsigned short* Ac = As0 + cur*8192;
    const unsigned short* Bc = Bs0 + cur*8192;
#pragma unroll
    for (int kk = 0; kk < 2; ++kk) {
      const int kc = kk*4 + l4;
      bf16x8 af[4], bfr[4];
#pragma unroll
      for (int i = 0; i < 4; ++i) {
        int m = wr + i*16 + l15;
        af[i] = *(const bf16x8*)(Ac + ((size_t)m*8 + kc)*8);
      }
#pragma unroll
      for (int j = 0; j < 4; ++j) {
        int n = wc + j*16 + l15;
        bfr[j] = *(const bf16x8*)(Bc + ((size_t)n*8 + kc)*8);
      }
#pragma unroll
      for (int i = 0; i < 4; ++i)
#pragma unroll
        for (int j = 0; j < 4; ++j)
          acc[i][j] = __builtin_amdgcn_mfma_f32_16x16x32_bf16(af[i], bfr[j], acc[i][j], 0, 0, 0);
    }
  }

  // ---- epilogue: spill C-tile to LDS fp32 [128][FS] ----
  WAIT_LGKM0(); BARRIER();
#pragma unroll
  for (int i = 0; i < 4; ++i)
#pragma unroll
    for (int j = 0; j < 4; ++j)
#pragma unroll
      for (int r = 0; r < 4; ++r) {
        const int row = wr + i*16 + l4*4 + r;
        const int col = wc + j*16 + l15;
        ftile[row*FS + col] = acc[i][j][r];
      }
  WAIT_LGKM0(); BARRIER();

  const int ny = n0 >> 7;                    // 0..15 q-head, 16..23 k-head, 24..31 v-head
  const int S0 = m0 & (SEQ-1);
  const int bb = m0 >> 11;

  if (ny < 24) {
    const bool isQ = ny < 16;
    {
      const int row = t >> 1, h2 = t & 1;
      const float* fr = ftile + row*FS + h2*64;
      float ssq = 0.f;
#pragma unroll
      for (int c = 0; c < 16; ++c) {
        float4 v = *(const float4*)(fr + 4*c);
        ssq += v.x*v.x + v.y*v.y + v.z*v.z + v.w*v.w;
      }
      ssq = dpp_addx1(ssq);
      if (h2 == 0) rinv[row] = rsqrtf(ssq*(1.0f/128.0f) + 1e-6f);
    }
    WAIT_LGKM0(); BARRIER();
    const float* wgt = isQ ? qw : kw;
    const int d = t & 127, rh = t >> 7;
    const float wd = wgt[d];
    const float w2 = wgt[d ^ 64];
    const float sgn = (d < 64) ? -1.f : 1.f;
    const float sOut = isQ ? 0.12751744f : 1.f;     // (1/sqrt(128))*log2(e) folded into q
    const float invf = exp2f(-(float)(d & 63) * 0.31143075889569023f);
    const int pos0 = pos_ids[S0 + rh*64];
    float cs, sn, dc, dsn;
    __sincosf((float)pos0 * invf, &sn, &cs);
    __sincosf(invf, &dsn, &dc);
    const int head = isQ ? ny : (ny - 16);
    unsigned short* dstb = isQ ? (q_l + ((size_t)(bb*NH + head)*SEQ + S0)*HD)
                               : (k_l + ((size_t)(bb*NKV + head)*SEQ + S0)*HD);
#pragma unroll 4
    for (int k = 0; k < 64; ++k) {
      const int row = rh*64 + k;
      const float r  = rinv[row];
      const float x1 = ftile[row*FS + d];
      const float x2 = ftile[row*FS + (d ^ 64)];
      const float y1 = x1*r*wd, y2 = x2*r*w2;
      const float o  = (y1*cs + sgn*(y2*sn)) * sOut;
      dstb[(size_t)row*HD + d] = f2bf(o);
      const float c2 = cs*dc - sn*dsn;       // rotate: pos -> pos+1
      sn = sn*dc + cs*dsn; cs = c2;
    }
  } else {
    // V-epilogue: kappa-permuted store. Slot (slice sl, elem s8) holds
    // C-row = blk*64 + s2*32 + e2*16 + s1*8 + s0*4 + e1*2 + e0.
    const int vh = ny - 24;
    unsigned short* vb = vt8 + (size_t)(bb*NKV + vh)*HD*SEQ;
    const int d = t & 127, sbh = t >> 7;
#pragma unroll
    for (int sb = 0; sb < 8; ++sb) {
      const int sl = sbh*8 + sb;
      const int blk = sl >> 3, s = sl & 7;
      const int base_r = blk*64 + ((s>>2)<<5) + (((s>>1)&1)<<3) + ((s&1)<<2);
      union { unsigned short u[8]; uint4 q; } pk;
#pragma unroll
      for (int s8 = 0; s8 < 8; ++s8) {
        const int row = base_r + ((s8>>2)<<4) + (((s8>>1)&1)<<1) + (s8&1);
        pk.u[s8] = f2bf(ftile[row*FS + d]);
      }
      *(uint4*)(vb + ((size_t)((S0 >> 3) + sl)*128 + d)*8) = pk.q;
    }
  }
}

// ------------- bf16 GEMM (out-proj): 128x128 tile, fp32 out -------------
__global__ __launch_bounds__(256) void gemm_out_kernel(
    const unsigned short* __restrict__ A,
    const unsigned short* __restrict__ Bt,
    float* __restrict__ Cout, int M, int N, int K) {
  constexpr int BK = 64;
  __shared__ unsigned short As[2][128*BK];   // 2 x 16 KB
  __shared__ unsigned short Bs[2][128*BK];   // 2 x 16 KB  -> 64 KB, 2 blocks/CU
  const int t = threadIdx.x, lane = t & 63, w = t >> 6;
  const int l15 = lane & 15, l4 = lane >> 4;
  const int wr = (w >> 1)*64, wc = (w & 1)*64;
  const int m0 = blockIdx.y * 128, n0 = blockIdx.x * 128;
  const unsigned short* Ab = A + (size_t)m0*K;
  const unsigned short* Bb = Bt + (size_t)n0*K;

  const f32x4 vzero = {0.f, 0.f, 0.f, 0.f};
  f32x4 acc[4][4];
#pragma unroll
  for (int i = 0; i < 4; ++i)
#pragma unroll
    for (int j = 0; j < 4; ++j) acc[i][j] = vzero;

  const int NIT = K / BK;
#pragma unroll
  for (int i = 0; i < 4; ++i) {
    const int c = (w*4 + i)*64 + lane;
    glds16(Ab + (size_t)(c >> 3)*K + (c & 7)*8, &As[0][(size_t)(w*4 + i)*512]);
  }
#pragma unroll
  for (int i = 0; i < 4; ++i) {
    const int c = (w*4 + i)*64 + lane;
    glds16(Bb + (size_t)(c >> 3)*K + (c & 7)*8, &Bs[0][(size_t)(w*4 + i)*512]);
  }

  for (int kb = 0; kb < NIT; ++kb) {
    const int cur = kb & 1;
    WAIT_LGKM0(); BARRIER();
    if (kb + 1 < NIT) {
      const int kn = (kb + 1) * BK;
#pragma unroll
      for (int i = 0; i < 4; ++i) {
        const int c = (w*4 + i)*64 + lane;
        glds16(Ab + (size_t)(c >> 3)*K + kn + (c & 7)*8, &As[cur^1][(size_t)(w*4 + i)*512]);
      }
#pragma unroll
      for (int i = 0; i < 4; ++i) {
        const int c = (w*4 + i)*64 + lane;
        glds16(Bb + (size_t)(c >> 3)*K + kn + (c & 7)*8, &Bs[cur^1][(size_t)(w*4 + i)*512]);
      }
      WAIT_VM8();
    } else {
      WAIT_VM0();
    }
    BARRIER();

#pragma unroll
    for (int kk = 0; kk < 2; ++kk) {
      const int kc = kk*4 + l4;
      bf16x8 af[4], bfr[4];
#pragma unroll
      for (int i = 0; i < 4; ++i) {
        int m = wr + i*16 + l15;
        af[i] = *(const bf16x8*)(&As[cur][((size_t)m*8 + kc)*8]);
      }
#pragma unroll
      for (int j = 0; j < 4; ++j) {
        int n = wc + j*16 + l15;
        bfr[j] = *(const bf16x8*)(&Bs[cur][((size_t)n*8 + kc)*8]);
      }
#pragma unroll
      for (int i = 0; i < 4; ++i)
#pragma unroll
        for (int j = 0; j < 4; ++j)
          acc[i][j] = __builtin_amdgcn_mfma_f32_16x16x32_bf16(af[i], bfr[j], acc[i][j], 0, 0, 0);
    }
  }
#pragma unroll
  for (int i = 0; i < 4; ++i)
#pragma unroll
    for (int j = 0; j < 4; ++j)
#pragma unroll
      for (int r = 0; r < 4; ++r) {
        int row = m0 + wr + i*16 + l4*4 + r;
        int col = n0 + wc + j*16 + l15;
        Cout[(size_t)row*N + col] = acc[i][j][r];
      }
}

// ------------- Flash attention, causal, GQA, KV-SPLIT (R14, proven 60.7us) -----
// R16: reverted from R15's 8-wave pair fusion (65.2us — occupancy doubled but
// MfmaUtil stayed 23%: attn is VALU/critical-path bound, NOT TLP-bound).
// R14 config: in-register-P datapath on R1's lockstep memory config (2-D grid
// hb-fast, K+V dbuf, 2 blocks/CU, WAIT_VM8 counted prefetch). FETCH compulsory.
__global__ __launch_bounds__(256, 2) void attn_kernel(
    const unsigned short* __restrict__ q_l,
    const unsigned short* __restrict__ k_l,
    const unsigned short* __restrict__ vt8,
    unsigned short* __restrict__ o_part,   // [2][B][NH][SEQ][HD] bf16
    float* __restrict__ l_part) {          // [2][B][NH][SEQ] fp32
  __shared__ __align__(16) char smem[65536];
  unsigned short* Ks0  = (unsigned short*)smem;            // 2 x 16 KB dbuf
  unsigned short* Vts0 = (unsigned short*)(smem + 32768);  // 2 x 16 KB dbuf

  const int t = threadIdx.x;
  const int lane = t & 63;
  const int w = t >> 6;
  const int l15 = lane & 15, l4 = lane >> 4;
  const int hb = blockIdx.x;                 // h + 16*b (fast dim: K/V L2 share)
  const int h = hb & 15, b = hb >> 4;
  const int y = blockIdx.y;                  // 0..31
  const int qt = 15 - (y >> 1);              // longest first
  const int half = y & 1;
  const int kvh = h >> 1;
  const int q0 = qt * 128;
  const int kt0 = half ? (qt + 1) : 0;
  const int kt1 = half ? (2*qt + 2) : (qt + 1);

  const unsigned short* Kg = k_l + ((size_t)(b*NKV + kvh)*SEQ)*HD;
  const unsigned short* Vg = vt8 + (size_t)(b*NKV + kvh)*HD*SEQ;
  const unsigned short* Qbase = q_l + ((size_t)(b*NH + h)*SEQ)*HD;

  const f32x4 vzero = {0.f,0.f,0.f,0.f};

  // Q fragments in registers (already scaled by 1/sqrt(d)*log2e)
  bf16x8 qf[2][4];
#pragma unroll
  for (int i = 0; i < 2; ++i) {
    const int row = q0 + w*32 + i*16 + l15;
    const unsigned short* Qp = Qbase + (size_t)row*HD;
#pragma unroll
    for (int kk = 0; kk < 4; ++kk)
      qf[i][kk] = *(const bf16x8*)(Qp + kk*32 + l4*8);
  }

  f32x4 oacc[2][8];                          // O^T: [q-subtile][d-tile]
#pragma unroll
  for (int i = 0; i < 2; ++i)
#pragma unroll
    for (int jd = 0; jd < 8; ++jd) oacc[i][jd] = vzero;
  float lrun[2] = {0.f, 0.f};                // per-lane partial row sums

  // prologue: issue K(kt0)+V(kt0) into buf 0 (8 loads/wave, R1 pattern)
  {
    const int k00 = kt0 * 64;
#pragma unroll
    for (int i = 0; i < 4; ++i) {            // K tile
      const int kc = w*4 + i;
      const int m = lane ^ (kc & 7);
      glds16(Kg + (size_t)(k00 + m)*HD + kc*8, Ks0 + (size_t)kc*64*8);
    }
#pragma unroll
    for (int i = 0; i < 4; ++i) {            // V tile (kappa-permuted vt8)
      const int id = w*4 + i;
      const int skc = id >> 1, hh = id & 1;
      const int d = (hh*64 + lane) ^ skc;
      glds16(Vg + ((size_t)((k00 >> 3) + skc)*128 + d)*8, Vts0 + (size_t)(skc*128 + hh*64)*8);
    }
  }

#pragma unroll 1
  for (int kt = kt0; kt < kt1; ++kt) {
    const int cur = (kt - kt0) & 1;
    const int k0 = kt * 64;
    WAIT_LGKM0(); BARRIER();                 // all waves done reading buf cur^1
    if (kt + 1 < kt1) {                      // prefetch kt+1 into buf cur^1
      const int kn = k0 + 64;
      unsigned short* Ksn  = Ks0  + (cur^1)*8192;
      unsigned short* Vtsn = Vts0 + (cur^1)*8192;
#pragma unroll
      for (int i = 0; i < 4; ++i) {
        const int kc = w*4 + i;
        const int m = lane ^ (kc & 7);
        glds16(Kg + (size_t)(kn + m)*HD + kc*8, Ksn + (size_t)kc*64*8);
      }
#pragma unroll
      for (int i = 0; i < 4; ++i) {
        const int id = w*4 + i;
        const int skc = id >> 1, hh = id & 1;
        const int d = (hh*64 + lane) ^ skc;
        glds16(Vg + ((size_t)((kn >> 3) + skc)*128 + d)*8, Vtsn + (size_t)(skc*128 + hh*64)*8);
      }
      WAIT_VM8();                             // drain only cur's 8 loads
    } else {
      WAIT_VM0();
    }
    BARRIER();                                // buf cur fully staged

    const unsigned short* KsC  = Ks0  + cur*8192;
    const unsigned short* VtsC = Vts0 + cur*8192;

    // S^T = K Q^T (lane: q = l15 within subtile, kv = j*16 + l4*4 + r)
    f32x4 sacc[4][2];
#pragma unroll
    for (int j = 0; j < 4; ++j)
#pragma unroll
      for (int i = 0; i < 2; ++i) sacc[j][i] = vzero;
    __builtin_amdgcn_s_setprio(1);
#pragma unroll
    for (int kk = 0; kk < 4; ++kk) {
      const int kc = kk*4 + l4;
      bf16x8 kb[4];
#pragma unroll
      for (int j = 0; j < 4; ++j) {
        int n = j*16 + l15;
        kb[j] = *(const bf16x8*)(KsC + ((size_t)kc*64 + (n ^ (kc & 7)))*8);
      }
#pragma unroll
      for (int j = 0; j < 4; ++j)
#pragma unroll
        for (int i = 0; i < 2; ++i)
          sacc[j][i] = __builtin_amdgcn_mfma_f32_16x16x32_bf16(kb[j], qf[i][kk], sacc[j][i], 0,0,0);
    }
    __builtin_amdgcn_s_setprio(0);

    // P = exp2(S) (no max); causal mask on the diag tiles
    const bool diag = (kt >= 2*qt);
#pragma unroll
    for (int j = 0; j < 4; ++j)
#pragma unroll
      for (int i = 0; i < 2; ++i)
#pragma unroll
        for (int r = 0; r < 4; ++r) {
          float sv = sacc[j][i][r];
          if (diag) {
            const int kvg = k0 + j*16 + l4*4 + r;
            const int qg  = q0 + w*32 + i*16 + l15;
            sv = (kvg > qg) ? -INFINITY : sv;
          }
          float pv = EXP2(sv);
          sacc[j][i][r] = pv;
          lrun[i] += pv;
        }

    // O^T += V^T P^T  (A = V^T frag from LDS, B = own packed P)
#pragma unroll
    for (int kk = 0; kk < 2; ++kk) {
      union { unsigned int u[4]; bf16x8 v; } pb[2];
#pragma unroll
      for (int i = 0; i < 2; ++i) {
        const f32x4 t0 = sacc[kk*2][i], t1 = sacc[kk*2+1][i];
        pb[i].u[0] = (__float_as_uint(t0[0]) >> 16) | (__float_as_uint(t0[1]) & 0xFFFF0000u);
        pb[i].u[1] = (__float_as_uint(t0[2]) >> 16) | (__float_as_uint(t0[3]) & 0xFFFF0000u);
        pb[i].u[2] = (__float_as_uint(t1[0]) >> 16) | (__float_as_uint(t1[1]) & 0xFFFF0000u);
        pb[i].u[3] = (__float_as_uint(t1[2]) >> 16) | (__float_as_uint(t1[3]) & 0xFFFF0000u);
      }
      const int s = kk*4 + l4;
      __builtin_amdgcn_s_setprio(1);
#pragma unroll
      for (int td = 0; td < 8; ++td) {
        const int dd = td*16 + l15;
        bf16x8 va = *(const bf16x8*)(VtsC + ((size_t)s*128 + (dd ^ s))*8);
#pragma unroll
        for (int i = 0; i < 2; ++i)
          oacc[i][td] = __builtin_amdgcn_mfma_f32_16x16x32_bf16(va, pb[i].v, oacc[i][td], 0,0,0);
      }
      __builtin_amdgcn_s_setprio(0);
    }
  }

  // epilogue: reduce lrun across the 4 l4-groups, normalize, store O^T.
  unsigned short* ob = o_part + ((size_t)half*BATCH*NH*SEQ + (size_t)(b*NH + h)*SEQ)*HD;
  float* lb = l_part + (size_t)half*BATCH*NH*SEQ + (size_t)(b*NH + h)*SEQ;
#pragma unroll
  for (int i = 0; i < 2; ++i) {
    float lsum = lrun[i];
    lsum += __shfl_xor(lsum, 16, 64);
    lsum += __shfl_xor(lsum, 32, 64);
    const float inv = (lsum > 0.f) ? 1.0f / lsum : 0.f;
    const int row = q0 + w*32 + i*16 + l15;
    if (l4 == 0) lb[row] = lsum;
#pragma unroll
    for (int td = 0; td < 8; ++td) {
      union { unsigned int u[2]; uint2 q; } pk;
      const float v0 = oacc[i][td][0]*inv, v1 = oacc[i][td][1]*inv;
      const float v2 = oacc[i][td][2]*inv, v3 = oacc[i][td][3]*inv;
      pk.u[0] = (unsigned int)f2bf(v0) | ((unsigned int)f2bf(v1) << 16);
      pk.u[1] = (unsigned int)f2bf(v2) | ((unsigned int)f2bf(v3) << 16);
      *(uint2*)(ob + (size_t)row*HD + td*16 + l4*4) = pk.q;
    }
  }
}

// ------------- combine: attn_o = (la*Oa + lb*Ob) / (la+lb) -------------
__global__ __launch_bounds__(256) void combine_kernel(
    const unsigned short* __restrict__ o_part,  // [2][B*NH*SEQ][HD] bf16
    const float* __restrict__ l_part,           // [2][B*NH*SEQ] fp32
    unsigned short* __restrict__ attn_o) {      // [B][SEQ][NH*HD] bf16
  const int tid = blockIdx.x * 256 + threadIdx.x;  // 1,048,576 threads
  const int d8 = tid & 15;                    // 16 chunks of 8 d
  const int row = tid >> 4;                   // (b*NH+h)*SEQ + s
  const int s = row & (SEQ-1);
  const int bh = row >> 11;
  const int h = bh & 15, b = bh >> 4;
  const float la = l_part[row];
  const float lbv = l_part[BATCH*NH*SEQ + row];
  const float inv = 1.f / (la + lbv);
  const float wa = la * inv, wb = lbv * inv;
  const unsigned short* pa = o_part + (size_t)row*HD + d8*8;
  const unsigned short* pb = pa + (size_t)BATCH*NH*SEQ*HD;
  uint4 ua = *(const uint4*)pa;
  uint4 ub = *(const uint4*)pb;
  const unsigned short* ea = (const unsigned short*)&ua;
  const unsigned short* eb = (const unsigned short*)&ub;
  union { unsigned short u[8]; uint4 q; } o;
#pragma unroll
  for (int k = 0; k < 8; ++k)
    o.u[k] = f2bf(bf2f(ea[k])*wa + bf2f(eb[k])*wb);
  *(uint4*)(attn_o + ((size_t)(b*SEQ + s)*(NH*HD)) + h*HD + d8*8) = o.q;
}

extern "C" void kernel_launch(void* const* d_in, const int* in_sizes, int n_in,
                              void* d_out, int out_size, void* d_ws, size_t ws_size,
                              hipStream_t stream) {
  const float* hs = (const float*)d_in[0];
  const int* pos  = (const int*)d_in[1];
  const float* Wq = (const float*)d_in[2];
  const float* Wk = (const float*)d_in[3];
  const float* Wv = (const float*)d_in[4];
  const float* Wo = (const float*)d_in[5];
  const float* qw = (const float*)d_in[6];
  const float* kw = (const float*)d_in[7];
  float* out = (float*)d_out;
  char* ws = (char*)d_ws;

  unsigned short* attn_o = (unsigned short*)(ws + 0);                    // 16 MB
  unsigned short* wot    = (unsigned short*)(ws + ((size_t)16 << 20));   // 4 MB
  unsigned short* q_l    = (unsigned short*)(ws + ((size_t)20 << 20));   // 16 MB
  unsigned short* k_l    = (unsigned short*)(ws + ((size_t)36 << 20));   // 8 MB
  unsigned short* vt8    = (unsigned short*)(ws + ((size_t)44 << 20));   // 8 MB
  unsigned short* o_part = (unsigned short*)(ws + ((size_t)52 << 20));   // 32 MB
  unsigned short* hsb    = (unsigned short*)(ws + ((size_t)52 << 20));   // 8 MB (alias)
  unsigned short* wqkvt  = (unsigned short*)(ws + ((size_t)60 << 20));   // 8 MB (alias)
  float*          l_part = (float*)(ws + ((size_t)84 << 20));            // 512 KB

  // 1. all converts in one launch (weights transpose-convert + hs convert)
  tcvt_all_kernel<<<dim3(7168), dim3(32, 8), 0, stream>>>(Wq, Wk, Wv, Wo, hs, wqkvt, wot, hsb);
  // 2. QKV projection + fused RMSNorm/RoPE/V-transpose epilogue (kappa-permuted vt8)
  gemm_qkv_fused_kernel<<<dim3(32, 32), dim3(256), 0, stream>>>(hsb, wqkvt, qw, kw, pos, q_l, k_l, vt8);
  // 3. flash attention: R14 config (in-register P, 2-D grid, dbuf K+V)
  attn_kernel<<<dim3(32, 32), dim3(256), 0, stream>>>(q_l, k_l, vt8, o_part, l_part);
  // 3b. combine partials -> attn_o
  combine_kernel<<<dim3(4096), dim3(256), 0, stream>>>(o_part, l_part, attn_o);
  // 4. output projection: 128x128 tiles, grid (N/128=8, M/128=32) = 256 blocks
  gemm_out_kernel<<<dim3(8, 32), dim3(256), 0, stream>>>(attn_o, wot, out, 4096, 1024, 2048);
}